// Round 1
// 5094.430 us; speedup vs baseline: 1.2686x; 1.2686x over previous
//
#include <hip/hip_runtime.h>
#include <hip/hip_bf16.h>
#include <math.h>

// Problem constants (fixed by the reference)
constexpr int Bc = 128, Tc = 16, Lc = 196, Ec = 512, Hc = 1024, Vc = 32000;

typedef float f32x4_t __attribute__((ext_vector_type(4)));
typedef short s16x8_t __attribute__((ext_vector_type(8)));

__device__ __forceinline__ float sigmoidf_(float x) { return 1.0f / (1.0f + expf(-x)); }

__device__ __forceinline__ unsigned short bf16rn(float x) {
    union { float f; unsigned u; } v; v.f = x;
    unsigned r = v.u + 0x7fffu + ((v.u >> 16) & 1u);
    return (unsigned short)(r >> 16);
}
__device__ __forceinline__ float bf16tof(unsigned short h) {
    union { unsigned u; float f; } v; v.u = ((unsigned)h) << 16; return v.f;
}

// ---------------------------------------------------------------------------
// Weight prep: src [K][N] f32 (row-major)  ->  dhi/dlo [N][ldd] bf16 bits
// (transposed + split into hi/lo bf16).  grid = (K/32, N/32), 256 threads.
// ---------------------------------------------------------------------------
__global__ __launch_bounds__(256)
void transpose_split(const float* __restrict__ src, int N,
                     unsigned short* __restrict__ dhi, unsigned short* __restrict__ dlo,
                     int ldd)
{
    __shared__ float tile[32][33];
    const int k0 = blockIdx.x * 32, n0 = blockIdx.y * 32;
    const int tx = threadIdx.x & 31, ty = threadIdx.x >> 5;  // ty 0..7
#pragma unroll
    for (int i = 0; i < 4; ++i)
        tile[ty + i * 8][tx] = src[(size_t)(k0 + ty + i * 8) * N + n0 + tx];
    __syncthreads();
#pragma unroll
    for (int i = 0; i < 4; ++i) {
        int nl = ty + i * 8;
        float v = tile[tx][nl];
        unsigned short hi = bf16rn(v);
        unsigned short lo = bf16rn(v - bf16tof(hi));
        size_t off = (size_t)(n0 + nl) * ldd + k0 + tx;
        dhi[off] = hi;
        dlo[off] = lo;
    }
}

// ---------------------------------------------------------------------------
// Split-bf16 MFMA GEMM: C[M,N] = A[M,K](f32) @ B[K,N] (+bias), where B is
// given pre-transposed/split: Bhi/Blo [N][K] bf16 bits.
// acc += Ahi*Bhi + Ahi*Blo + Alo*Bhi   (lo*lo dropped, ~2^-18 relative)
// Block: 256 thr = 4 waves (2x2), tile 128x128, BK=32, 16x16x32 MFMA.
// PIPELINED: LDS double-buffered, globals prefetched 2 K-tiles ahead,
// single barrier per K-step. Targets the latency-bound skinny-GEMM regime
// (grid gives ~1 wave/SIMD, so no TLP exists to hide load latency).
// Requires M%128==0, N%128==0, K%32==0 (K>=64). grid = (M/128, N/128).
// ---------------------------------------------------------------------------
__global__ __launch_bounds__(256)
void gemm_mfma_split(const float* __restrict__ A, int lda,
                     const unsigned short* __restrict__ Bhi,
                     const unsigned short* __restrict__ Blo,
                     float* __restrict__ C, long ldc,
                     const float* __restrict__ bias, int K)
{
    __shared__ __align__(16) unsigned short As_hi[2][128][32];
    __shared__ __align__(16) unsigned short As_lo[2][128][32];
    __shared__ __align__(16) unsigned short Bs_hi[2][128][32];
    __shared__ __align__(16) unsigned short Bs_lo[2][128][32];

    const int t = threadIdx.x;
    const int wave = t >> 6, lane = t & 63;
    const int wr = wave >> 1, wc = wave & 1;   // wave 2x2 within 128x128 tile
    const int lm = lane & 15, qd = lane >> 4;  // fragment coords
    const size_t m0 = (size_t)blockIdx.x * 128;
    const size_t n0 = (size_t)blockIdx.y * 128;

    // staging assignment: thread -> (row = t>>1, k-half = (t&1)*16)
    const int srow = t >> 1;
    const int skh  = (t & 1) * 16;

    const float* Ap = A + (m0 + srow) * (size_t)lda + skh;
    const unsigned short* Bhp = Bhi + (n0 + srow) * (size_t)K + skh;
    const unsigned short* Blp = Blo + (n0 + srow) * (size_t)K + skh;

    const int nk = K >> 5;

    f32x4_t acc[4][4];
#pragma unroll
    for (int i = 0; i < 4; ++i)
#pragma unroll
        for (int j = 0; j < 4; ++j)
            acc[i][j] = (f32x4_t){0.f, 0.f, 0.f, 0.f};

    // register staging for the in-flight K-tile
    float av[16];
    s16x8_t sbh0, sbh1, sbl0, sbl1;

#define G_LOAD(k0_)                                              \
    do {                                                         \
        *(float4*)&av[0]  = *(const float4*)(Ap + (k0_));        \
        *(float4*)&av[4]  = *(const float4*)(Ap + (k0_) + 4);    \
        *(float4*)&av[8]  = *(const float4*)(Ap + (k0_) + 8);    \
        *(float4*)&av[12] = *(const float4*)(Ap + (k0_) + 12);   \
        sbh0 = *(const s16x8_t*)(Bhp + (k0_));                   \
        sbh1 = *(const s16x8_t*)(Bhp + (k0_) + 8);               \
        sbl0 = *(const s16x8_t*)(Blp + (k0_));                   \
        sbl1 = *(const s16x8_t*)(Blp + (k0_) + 8);               \
    } while (0)

#define LDS_STORE(buf_)                                          \
    do {                                                         \
        s16x8_t h0, h1, l0, l1;                                  \
        _Pragma("unroll")                                        \
        for (int i = 0; i < 8; ++i) {                            \
            unsigned short hi = bf16rn(av[i]);                   \
            h0[i] = (short)hi;                                   \
            l0[i] = (short)bf16rn(av[i] - bf16tof(hi));          \
        }                                                        \
        _Pragma("unroll")                                        \
        for (int i = 0; i < 8; ++i) {                            \
            unsigned short hi = bf16rn(av[8 + i]);               \
            h1[i] = (short)hi;                                   \
            l1[i] = (short)bf16rn(av[8 + i] - bf16tof(hi));      \
        }                                                        \
        *(s16x8_t*)&As_hi[buf_][srow][skh]     = h0;             \
        *(s16x8_t*)&As_hi[buf_][srow][skh + 8] = h1;             \
        *(s16x8_t*)&As_lo[buf_][srow][skh]     = l0;             \
        *(s16x8_t*)&As_lo[buf_][srow][skh + 8] = l1;             \
        *(s16x8_t*)&Bs_hi[buf_][srow][skh]     = sbh0;           \
        *(s16x8_t*)&Bs_hi[buf_][srow][skh + 8] = sbh1;           \
        *(s16x8_t*)&Bs_lo[buf_][srow][skh]     = sbl0;           \
        *(s16x8_t*)&Bs_lo[buf_][srow][skh + 8] = sbl1;           \
    } while (0)

    // prologue: tile 0 into LDS[0], tile 1 in flight in registers
    G_LOAD(0);
    LDS_STORE(0);
    if (nk > 1) G_LOAD(32);
    __syncthreads();

    for (int k = 0; k < nk; ++k) {
        const int cur = k & 1;
        // issue this tile's fragment reads first (lgkm in flight)
        s16x8_t ah[4], al[4], bh[4], bl[4];
#pragma unroll
        for (int mt = 0; mt < 4; ++mt) {
            ah[mt] = *(const s16x8_t*)&As_hi[cur][wr * 64 + mt * 16 + lm][qd * 8];
            al[mt] = *(const s16x8_t*)&As_lo[cur][wr * 64 + mt * 16 + lm][qd * 8];
        }
#pragma unroll
        for (int nt = 0; nt < 4; ++nt) {
            bh[nt] = *(const s16x8_t*)&Bs_hi[cur][wc * 64 + nt * 16 + lm][qd * 8];
            bl[nt] = *(const s16x8_t*)&Bs_lo[cur][wc * 64 + nt * 16 + lm][qd * 8];
        }
        // drain in-flight registers into the other LDS buffer, then issue
        // the next prefetch (2 tiles ahead) before the MFMA cluster
        if (k + 1 < nk) {
            LDS_STORE(cur ^ 1);
            if (k + 2 < nk) G_LOAD((k + 2) << 5);
        }
#pragma unroll
        for (int mt = 0; mt < 4; ++mt)
#pragma unroll
            for (int nt = 0; nt < 4; ++nt) {
                acc[mt][nt] = __builtin_amdgcn_mfma_f32_16x16x32_bf16(ah[mt], bh[nt], acc[mt][nt], 0, 0, 0);
                acc[mt][nt] = __builtin_amdgcn_mfma_f32_16x16x32_bf16(ah[mt], bl[nt], acc[mt][nt], 0, 0, 0);
                acc[mt][nt] = __builtin_amdgcn_mfma_f32_16x16x32_bf16(al[mt], bh[nt], acc[mt][nt], 0, 0, 0);
            }
        __syncthreads();
    }
#undef G_LOAD
#undef LDS_STORE

    // epilogue: C/D layout col=lane&15, row=qd*4+reg
#pragma unroll
    for (int nt = 0; nt < 4; ++nt) {
        size_t n = n0 + wc * 64 + nt * 16 + lm;
        float bs = bias ? bias[n] : 0.f;
#pragma unroll
        for (int mt = 0; mt < 4; ++mt) {
#pragma unroll
            for (int r = 0; r < 4; ++r) {
                size_t m = m0 + wr * 64 + mt * 16 + qd * 4 + r;
                C[(size_t)m * ldc + n] = acc[mt][nt][r] + bs;
            }
        }
    }
}

// concat two f32 vectors
__global__ __launch_bounds__(256)
void concat2(const float* __restrict__ a, int na, const float* __restrict__ b, int nb,
             float* __restrict__ out)
{
    int i = blockIdx.x * 256 + threadIdx.x;
    if (i < na) out[i] = a[i];
    else if (i < na + nb) out[i] = b[i - na];
}

// mean over L: mean_a[b,e] = (1/L) * sum_l feats[b,l,e]   grid=(B, E/256)
__global__ __launch_bounds__(256)
void mean_kernel(const float* __restrict__ feats, float* __restrict__ mean_a)
{
    int b = blockIdx.x;
    int e = blockIdx.y * 256 + threadIdx.x;
    const float* f = feats + ((size_t)b * Lc) * Ec + e;
    float s = 0.f;
    for (int l = 0; l < Lc; ++l) s += f[(size_t)l * Ec];
    mean_a[b * Ec + e] = s * (1.0f / Lc);
}

// e[b,l] = sum_h relu(q[b,h] + keys[b,l,h]) * V_a[h] + b_va ; ldq = q row stride
__global__ __launch_bounds__(256)
void att_scores(const float* __restrict__ q, int ldq, const float* __restrict__ keys,
                const float* __restrict__ V_a, const float* __restrict__ b_va,
                float* __restrict__ e)
{
    int pair = blockIdx.x * 4 + (threadIdx.x >> 6);
    int lane = threadIdx.x & 63;
    int b = pair / Lc;
    const float* qp = q + (size_t)b * ldq;
    const float* kp = keys + (size_t)pair * Hc;
    float s = 0.f;
    for (int h = lane; h < Hc; h += 64)
        s = fmaf(fmaxf(qp[h] + kp[h], 0.f), V_a[h], s);
#pragma unroll
    for (int off = 32; off > 0; off >>= 1) s += __shfl_down(s, off);
    if (lane == 0) e[pair] = s + b_va[0];
}

// softmax over L (in place on e[b,:]), grid = B
__global__ __launch_bounds__(256)
void softmax_L(float* __restrict__ e)
{
    int b = blockIdx.x;
    float* p = e + b * Lc;
    __shared__ float red[256];
    int tid = threadIdx.x;
    float m = -1e30f;
    if (tid < Lc) m = p[tid];
    red[tid] = m; __syncthreads();
    for (int s = 128; s > 0; s >>= 1) { if (tid < s) red[tid] = fmaxf(red[tid], red[tid + s]); __syncthreads(); }
    m = red[0]; __syncthreads();
    float ex = 0.f;
    if (tid < Lc) ex = expf(p[tid] - m);
    red[tid] = ex; __syncthreads();
    for (int s = 128; s > 0; s >>= 1) { if (tid < s) red[tid] += red[tid + s]; __syncthreads(); }
    if (tid < Lc) p[tid] = ex / red[0];
}

// z[b,e] = sum_l alpha[b,l] * feats[b,l,e]   grid=(B, E/256)
__global__ __launch_bounds__(256)
void z_kernel(const float* __restrict__ alpha, const float* __restrict__ feats,
              float* __restrict__ z)
{
    int b = blockIdx.x;
    int e = blockIdx.y * 256 + threadIdx.x;
    const float* f = feats + ((size_t)b * Lc) * Ec + e;
    const float* a = alpha + b * Lc;
    float s = 0.f;
    for (int l = 0; l < Lc; ++l) s = fmaf(a[l], f[(size_t)l * Ec], s);
    z[b * Ec + e] = s;
}

// fast path: xcat[b] = [z*sigmoid(sb) | emb[tok] | h]  (2048 wide), grid=(B,8)
__global__ __launch_bounds__(256)
void xcat_build(const float* __restrict__ z, const float* __restrict__ qsb,
                const int* __restrict__ caption, const float* __restrict__ emb,
                const float* __restrict__ hc, float* __restrict__ xcat, int t)
{
    int b = blockIdx.x;
    int j = blockIdx.y * 256 + threadIdx.x;
    float v;
    if (j < Ec) {
        float sb = qsb[(size_t)b * 1536 + 1024 + j];
        v = z[b * Ec + j] * sigmoidf_(sb);
    } else if (j < 2 * Ec) {
        int tok = caption[b * Tc + t];
        v = emb[(size_t)tok * Ec + (j - Ec)];
    } else {
        v = hc[(size_t)b * 2048 + (j - 2 * Ec)];
    }
    xcat[(size_t)b * 2048 + j] = v;
}

// legacy ctx build: ctx[b] = [z*sigmoid(sb) | emb[tok]] (1024 wide), grid=(B,4)
__global__ __launch_bounds__(256)
void ctx_build(const float* __restrict__ z, const float* __restrict__ sb,
               const int* __restrict__ caption, const float* __restrict__ emb,
               float* __restrict__ ctx, int t)
{
    int b = blockIdx.x;
    int j = blockIdx.y * 256 + threadIdx.x;
    float v;
    if (j < Ec) {
        v = z[b * Ec + j] * sigmoidf_(sb[b * Ec + j]);
    } else {
        int tok = caption[b * Tc + t];
        v = emb[(size_t)tok * Ec + (j - Ec)];
    }
    ctx[b * (2 * Ec) + j] = v;
}

// LSTM elementwise; h at hbase[b*ld + j], c at cbase[b*ld + j]. grid=B*H/256
__global__ __launch_bounds__(256)
void lstm_elem(const float* __restrict__ gates, float* __restrict__ hbase,
               float* __restrict__ cbase, int ld)
{
    int idx = blockIdx.x * 256 + threadIdx.x;
    int b = idx >> 10;
    int j = idx & (Hc - 1);
    const float* g = gates + (size_t)b * 4 * Hc;
    float gi = g[j], gf = g[Hc + j], gg = g[2 * Hc + j], go = g[3 * Hc + j];
    float* cp = cbase + (size_t)b * ld + j;
    float* hp = hbase + (size_t)b * ld + j;
    float cn = sigmoidf_(gf) * (*cp) + sigmoidf_(gi) * tanhf(gg);
    *cp = cn;
    *hp = sigmoidf_(go) * tanhf(cn);
}

// softmax over V in place on out[b,t,:]. grid = B
__global__ __launch_bounds__(256)
void softmax_V(float* __restrict__ out, int t)
{
    int b = blockIdx.x;
    float* p = out + ((size_t)b * Tc + t) * (size_t)Vc;
    __shared__ float red[256];
    int tid = threadIdx.x;
    float m = -1e30f;
    for (int v = tid; v < Vc; v += 256) m = fmaxf(m, p[v]);
    red[tid] = m; __syncthreads();
    for (int s = 128; s > 0; s >>= 1) { if (tid < s) red[tid] = fmaxf(red[tid], red[tid + s]); __syncthreads(); }
    m = red[0]; __syncthreads();
    float sum = 0.f;
    for (int v = tid; v < Vc; v += 256) { float ex = expf(p[v] - m); p[v] = ex; sum += ex; }
    red[tid] = sum; __syncthreads();
    for (int s = 128; s > 0; s >>= 1) { if (tid < s) red[tid] += red[tid + s]; __syncthreads(); }
    float inv = 1.0f / red[0];
    __syncthreads();
    for (int v = tid; v < Vc; v += 256) p[v] *= inv;
}

// ---------------------------------------------------------------------------
// Legacy f32 tiled GEMM (fallback path if workspace too small)
// ---------------------------------------------------------------------------
__global__ __launch_bounds__(256)
void gemm_f32(const float* __restrict__ A, int lda,
              const float* __restrict__ Bm, int ldb,
              float* __restrict__ C, int ldc,
              const float* __restrict__ bias,
              int K, int accumulate)
{
    __shared__ __align__(16) float As[16][68];
    __shared__ __align__(16) float Bs[16][68];
    const int t  = threadIdx.x;
    const int tx = t & 15;
    const int ty = t >> 4;
    const size_t m0 = (size_t)blockIdx.x * 64;
    const size_t n0 = (size_t)blockIdx.y * 64;
    const int arow = t >> 2;
    const int acol = (t & 3) << 2;
    const int brow = t >> 4;
    const int bcol = (t & 15) << 2;
    const float* Aptr = A + (m0 + arow) * (size_t)lda + acol;
    const float* Bptr = Bm + (size_t)brow * ldb + n0 + bcol;
    float acc[4][4] = {};
    for (int k0 = 0; k0 < K; k0 += 16) {
        float4 av = *reinterpret_cast<const float4*>(Aptr + k0);
        float4 bv = *reinterpret_cast<const float4*>(Bptr + (size_t)k0 * ldb);
        As[acol + 0][arow] = av.x;
        As[acol + 1][arow] = av.y;
        As[acol + 2][arow] = av.z;
        As[acol + 3][arow] = av.w;
        *reinterpret_cast<float4*>(&Bs[brow][bcol]) = bv;
        __syncthreads();
#pragma unroll
        for (int k = 0; k < 16; ++k) {
            float4 a4 = *reinterpret_cast<const float4*>(&As[k][ty << 2]);
            float4 b4 = *reinterpret_cast<const float4*>(&Bs[k][tx << 2]);
            float aa[4] = {a4.x, a4.y, a4.z, a4.w};
            float bb[4] = {b4.x, b4.y, b4.z, b4.w};
#pragma unroll
            for (int i = 0; i < 4; ++i)
#pragma unroll
                for (int j = 0; j < 4; ++j)
                    acc[i][j] = fmaf(aa[i], bb[j], acc[i][j]);
        }
        __syncthreads();
    }
    float4 bv4 = {0.f, 0.f, 0.f, 0.f};
    if (bias) bv4 = *reinterpret_cast<const float4*>(&bias[n0 + (tx << 2)]);
#pragma unroll
    for (int i = 0; i < 4; ++i) {
        size_t off = (m0 + (size_t)(ty << 2) + i) * (size_t)ldc + n0 + (tx << 2);
        float4 o;
        o.x = acc[i][0] + bv4.x;
        o.y = acc[i][1] + bv4.y;
        o.z = acc[i][2] + bv4.z;
        o.w = acc[i][3] + bv4.w;
        if (accumulate) {
            float4 prev = *reinterpret_cast<const float4*>(&C[off]);
            o.x += prev.x; o.y += prev.y; o.z += prev.z; o.w += prev.w;
        }
        *reinterpret_cast<float4*>(&C[off]) = o;
    }
}

extern "C" void kernel_launch(void* const* d_in, const int* in_sizes, int n_in,
                              void* d_out, int out_size, void* d_ws, size_t ws_size,
                              hipStream_t stream)
{
    const int*   caption  = (const int*)  d_in[0];
    const float* feats    = (const float*)d_in[1];
    const float* emb      = (const float*)d_in[2];
    const float* W_init_h = (const float*)d_in[3];
    const float* b_init_h = (const float*)d_in[4];
    const float* W_init_c = (const float*)d_in[5];
    const float* b_init_c = (const float*)d_in[6];
    const float* W_a      = (const float*)d_in[7];
    const float* b_a      = (const float*)d_in[8];
    const float* U_a      = (const float*)d_in[9];
    const float* b_ua     = (const float*)d_in[10];
    const float* V_a      = (const float*)d_in[11];
    const float* b_va     = (const float*)d_in[12];
    const float* W_beta   = (const float*)d_in[13];
    const float* b_beta   = (const float*)d_in[14];
    const float* W_lstm   = (const float*)d_in[15];
    const float* U_lstm   = (const float*)d_in[16];
    const float* b_lstm   = (const float*)d_in[17];
    const float* W_out    = (const float*)d_in[18];
    const float* b_out    = (const float*)d_in[19];
    float* out = (float*)d_out;

    dim3 blk(256);

    // ---------------- fast-path workspace layout (bytes) ----------------
    char* base = (char*)d_ws;
    size_t off = 0;
    auto alloc = [&](size_t bytes) { char* p = base + off; off = (off + bytes + 15) & ~(size_t)15; return p; };

    float* keys   = (float*)alloc((size_t)Bc * Lc * Hc * 4);
    float* hc     = (float*)alloc((size_t)Bc * 2048 * 4);      // h | c interleaved per row
    float* qsb    = (float*)alloc((size_t)Bc * 1536 * 4);      // q | sb
    float* e      = (float*)alloc((size_t)Bc * Lc * 4);
    float* z      = (float*)alloc((size_t)Bc * Ec * 4);
    float* xcat   = (float*)alloc((size_t)Bc * 2048 * 4);      // z*sig | emb | h
    float* gates  = (float*)alloc((size_t)Bc * 4 * Hc * 4);
    float* mean_a = (float*)alloc((size_t)Bc * Ec * 4);
    float* bcat_i = (float*)alloc(2048 * 4);
    float* bcat_q = (float*)alloc(1536 * 4);
    unsigned short* Wout_hi  = (unsigned short*)alloc((size_t)Vc * Hc * 2);
    unsigned short* Wout_lo  = (unsigned short*)alloc((size_t)Vc * Hc * 2);
    unsigned short* Wg_hi    = (unsigned short*)alloc((size_t)4096 * 2048 * 2);
    unsigned short* Wg_lo    = (unsigned short*)alloc((size_t)4096 * 2048 * 2);
    unsigned short* Wqsb_hi  = (unsigned short*)alloc((size_t)1536 * 1024 * 2);
    unsigned short* Wqsb_lo  = (unsigned short*)alloc((size_t)1536 * 1024 * 2);
    unsigned short* Ua_hi    = (unsigned short*)alloc((size_t)1024 * 512 * 2);
    unsigned short* Ua_lo    = (unsigned short*)alloc((size_t)1024 * 512 * 2);
    unsigned short* Wini_hi  = (unsigned short*)alloc((size_t)2048 * 512 * 2);
    unsigned short* Wini_lo  = (unsigned short*)alloc((size_t)2048 * 512 * 2);
    const size_t need_fast = off;

    if (ws_size >= need_fast) {
        // ================= fast path: split-bf16 MFMA =================
        // ---- weight prep (per call; same work every call) ----
        transpose_split<<<dim3(16, 32), blk, 0, stream>>>(U_a, 1024, Ua_hi, Ua_lo, 512);
        transpose_split<<<dim3(16, 32), blk, 0, stream>>>(W_init_h, 1024, Wini_hi, Wini_lo, 512);
        transpose_split<<<dim3(16, 32), blk, 0, stream>>>(W_init_c, 1024, Wini_hi + (size_t)1024 * 512, Wini_lo + (size_t)1024 * 512, 512);
        transpose_split<<<dim3(32, 32), blk, 0, stream>>>(W_a, 1024, Wqsb_hi, Wqsb_lo, 1024);
        transpose_split<<<dim3(32, 16), blk, 0, stream>>>(W_beta, 512, Wqsb_hi + (size_t)1024 * 1024, Wqsb_lo + (size_t)1024 * 1024, 1024);
        transpose_split<<<dim3(32, 128), blk, 0, stream>>>(W_lstm, 4096, Wg_hi, Wg_lo, 2048);
        transpose_split<<<dim3(32, 128), blk, 0, stream>>>(U_lstm, 4096, Wg_hi + 1024, Wg_lo + 1024, 2048);
        transpose_split<<<dim3(32, 1000), blk, 0, stream>>>(W_out, Vc, Wout_hi, Wout_lo, 1024);
        concat2<<<dim3(8), blk, 0, stream>>>(b_init_h, 1024, b_init_c, 1024, bcat_i);
        concat2<<<dim3(6), blk, 0, stream>>>(b_a, 1024, b_beta, 512, bcat_q);

        // ---- setup ----
        mean_kernel<<<dim3(Bc, 2), blk, 0, stream>>>(feats, mean_a);
        // hc = mean_a @ [W_init_h | W_init_c] + [b_init_h | b_init_c]
        gemm_mfma_split<<<dim3(1, 16), blk, 0, stream>>>(mean_a, Ec, Wini_hi, Wini_lo, hc, 2048, bcat_i, 512);
        // keys = feats @ U_a + b_ua
        gemm_mfma_split<<<dim3((Bc * Lc) / 128, 8), blk, 0, stream>>>(feats, Ec, Ua_hi, Ua_lo, keys, Hc, b_ua, 512);

        // ---- time steps ----
        for (int t = 0; t < Tc; ++t) {
            // qsb = h @ [W_a | W_beta] + [b_a | b_beta]
            gemm_mfma_split<<<dim3(1, 12), blk, 0, stream>>>(hc, 2048, Wqsb_hi, Wqsb_lo, qsb, 1536, bcat_q, 1024);
            att_scores<<<dim3((Bc * Lc) / 4), blk, 0, stream>>>(qsb, 1536, keys, V_a, b_va, e);
            softmax_L<<<dim3(Bc), blk, 0, stream>>>(e);
            z_kernel<<<dim3(Bc, 2), blk, 0, stream>>>(e, feats, z);
            xcat_build<<<dim3(Bc, 8), blk, 0, stream>>>(z, qsb, caption, emb, hc, xcat, t);
            // gates = [ctx | h] @ [W_lstm ; U_lstm] + b_lstm
            gemm_mfma_split<<<dim3(1, 32), blk, 0, stream>>>(xcat, 2048, Wg_hi, Wg_lo, gates, 4096, b_lstm, 2048);
            lstm_elem<<<dim3((Bc * Hc) / 256), blk, 0, stream>>>(gates, hc, hc + 1024, 2048);
            // logits into d_out slice, softmax in place
            gemm_mfma_split<<<dim3(1, 250), blk, 0, stream>>>(hc, 2048, Wout_hi, Wout_lo, out + (size_t)t * Vc, (long)Tc * Vc, b_out, 1024);
            softmax_V<<<dim3(Bc), blk, 0, stream>>>(out, t);
        }
        return;
    }

    // ================= legacy f32 fallback =================
    float* ws = (float*)d_ws;
    size_t foff = 0;
    float* l_keys  = ws + foff; foff += (size_t)Bc * Lc * Hc;
    float* l_h     = ws + foff; foff += (size_t)Bc * Hc;
    float* l_c     = ws + foff; foff += (size_t)Bc * Hc;
    float* l_q     = ws + foff; foff += (size_t)Bc * Hc;
    float* l_e     = ws + foff; foff += (size_t)Bc * Lc;
    float* l_sb    = ws + foff; foff += (size_t)Bc * Ec;
    float* l_z     = ws + foff; foff += (size_t)Bc * Ec;
    float* l_ctx   = ws + foff; foff += (size_t)Bc * 2 * Ec;
    float* l_gates = ws + foff; foff += (size_t)Bc * 4 * Hc;
    float* l_mean  = ws + foff; foff += (size_t)Bc * Ec;
    if (ws_size < foff * sizeof(float)) return;

    mean_kernel<<<dim3(Bc, 2), blk, 0, stream>>>(feats, l_mean);
    gemm_f32<<<dim3(Bc / 64, Hc / 64), blk, 0, stream>>>(l_mean, Ec, W_init_h, Hc, l_h, Hc, b_init_h, Ec, 0);
    gemm_f32<<<dim3(Bc / 64, Hc / 64), blk, 0, stream>>>(l_mean, Ec, W_init_c, Hc, l_c, Hc, b_init_c, Ec, 0);
    gemm_f32<<<dim3((Bc * Lc) / 64, Hc / 64), blk, 0, stream>>>(feats, Ec, U_a, Hc, l_keys, Hc, b_ua, Ec, 0);
    for (int t = 0; t < Tc; ++t) {
        gemm_f32<<<dim3(Bc / 64, Hc / 64), blk, 0, stream>>>(l_h, Hc, W_a, Hc, l_q, Hc, b_a, Hc, 0);
        att_scores<<<dim3((Bc * Lc) / 4), blk, 0, stream>>>(l_q, Hc, l_keys, V_a, b_va, l_e);
        softmax_L<<<dim3(Bc), blk, 0, stream>>>(l_e);
        z_kernel<<<dim3(Bc, 2), blk, 0, stream>>>(l_e, feats, l_z);
        gemm_f32<<<dim3(Bc / 64, Ec / 64), blk, 0, stream>>>(l_h, Hc, W_beta, Ec, l_sb, Ec, b_beta, Hc, 0);
        ctx_build<<<dim3(Bc, 4), blk, 0, stream>>>(l_z, l_sb, caption, emb, l_ctx, t);
        gemm_f32<<<dim3(Bc / 64, (4 * Hc) / 64), blk, 0, stream>>>(l_ctx, 2 * Ec, W_lstm, 4 * Hc, l_gates, 4 * Hc, b_lstm, 2 * Ec, 0);
        gemm_f32<<<dim3(Bc / 64, (4 * Hc) / 64), blk, 0, stream>>>(l_h, Hc, U_lstm, 4 * Hc, l_gates, 4 * Hc, nullptr, Hc, 1);
        lstm_elem<<<dim3((Bc * Hc) / 256), blk, 0, stream>>>(l_gates, l_h, l_c, Hc);
        gemm_f32<<<dim3(Bc / 64, Vc / 64), blk, 0, stream>>>(l_h, Hc, W_out, Vc, out + (size_t)t * Vc, Tc * Vc, b_out, Hc, 0);
        softmax_V<<<dim3(Bc), blk, 0, stream>>>(out, t);
    }
}

// Round 2
// 3285.646 us; speedup vs baseline: 1.9669x; 1.5505x over previous
//
#include <hip/hip_runtime.h>
#include <hip/hip_bf16.h>
#include <math.h>

// Problem constants (fixed by the reference)
constexpr int Bc = 128, Tc = 16, Lc = 196, Ec = 512, Hc = 1024, Vc = 32000;

typedef float f32x4_t __attribute__((ext_vector_type(4)));
typedef short s16x8_t __attribute__((ext_vector_type(8)));

__device__ __forceinline__ float sigmoidf_(float x) { return 1.0f / (1.0f + expf(-x)); }

__device__ __forceinline__ unsigned short bf16rn(float x) {
    union { float f; unsigned u; } v; v.f = x;
    unsigned r = v.u + 0x7fffu + ((v.u >> 16) & 1u);
    return (unsigned short)(r >> 16);
}
__device__ __forceinline__ float bf16tof(unsigned short h) {
    union { unsigned u; float f; } v; v.u = ((unsigned)h) << 16; return v.f;
}

// ---------------------------------------------------------------------------
// Weight prep: src [K][N] f32 (row-major)  ->  dhi/dlo [N][ldd] bf16 bits
// (transposed + split into hi/lo bf16).  grid = (K/32, N/32), 256 threads.
// ---------------------------------------------------------------------------
__global__ __launch_bounds__(256)
void transpose_split(const float* __restrict__ src, int N,
                     unsigned short* __restrict__ dhi, unsigned short* __restrict__ dlo,
                     int ldd)
{
    __shared__ float tile[32][33];
    const int k0 = blockIdx.x * 32, n0 = blockIdx.y * 32;
    const int tx = threadIdx.x & 31, ty = threadIdx.x >> 5;  // ty 0..7
#pragma unroll
    for (int i = 0; i < 4; ++i)
        tile[ty + i * 8][tx] = src[(size_t)(k0 + ty + i * 8) * N + n0 + tx];
    __syncthreads();
#pragma unroll
    for (int i = 0; i < 4; ++i) {
        int nl = ty + i * 8;
        float v = tile[tx][nl];
        unsigned short hi = bf16rn(v);
        unsigned short lo = bf16rn(v - bf16tof(hi));
        size_t off = (size_t)(n0 + nl) * ldd + k0 + tx;
        dhi[off] = hi;
        dlo[off] = lo;
    }
}

// ---------------------------------------------------------------------------
// Split-bf16 MFMA GEMM: C[M,N] = A[M,K](f32) @ B[K,N] (+bias), B pre-
// transposed/split: Bhi/Blo [N][K] bf16 bits.
// acc += Ahi*Bhi + Ahi*Blo + Alo*Bhi   (lo*lo dropped, ~2^-18 relative)
// Block: 256 thr = 4 waves (2x2), tile 128x128, BK=32, 16x16x32 MFMA.
// PIPELINED (LDS dbuf + 2-deep register prefetch, 1 barrier per K-step).
// SPLIT-K via gridDim.z: slice z handles K/gridDim.z contiguous K; its
// output goes to C + z*cslice (bias must be nullptr for split calls —
// consumers sum the partials + bias). K/gridDim.z must be %32==0, >=64.
// ---------------------------------------------------------------------------
__global__ __launch_bounds__(256)
void gemm_mfma_split(const float* __restrict__ A, int lda,
                     const unsigned short* __restrict__ Bhi,
                     const unsigned short* __restrict__ Blo,
                     float* __restrict__ C, long ldc,
                     const float* __restrict__ bias, int K, long cslice)
{
    __shared__ __align__(16) unsigned short As_hi[2][128][32];
    __shared__ __align__(16) unsigned short As_lo[2][128][32];
    __shared__ __align__(16) unsigned short Bs_hi[2][128][32];
    __shared__ __align__(16) unsigned short Bs_lo[2][128][32];

    const int t = threadIdx.x;
    const int wave = t >> 6, lane = t & 63;
    const int wr = wave >> 1, wc = wave & 1;   // wave 2x2 within 128x128 tile
    const int lm = lane & 15, qd = lane >> 4;  // fragment coords
    const size_t m0 = (size_t)blockIdx.x * 128;
    const size_t n0 = (size_t)blockIdx.y * 128;

    const int S   = gridDim.z;
    const int ksl = blockIdx.z;
    const int Ksl = K / S;            // caller guarantees %32==0, >=64
    const int kbase = ksl * Ksl;

    // staging assignment: thread -> (row = t>>1, k-half = (t&1)*16)
    const int srow = t >> 1;
    const int skh  = (t & 1) * 16;

    const float* Ap = A + (m0 + srow) * (size_t)lda + skh + kbase;
    const unsigned short* Bhp = Bhi + (n0 + srow) * (size_t)K + skh + kbase;
    const unsigned short* Blp = Blo + (n0 + srow) * (size_t)K + skh + kbase;

    const int nk = Ksl >> 5;
    float* Cp = C + (size_t)ksl * cslice;

    f32x4_t acc[4][4];
#pragma unroll
    for (int i = 0; i < 4; ++i)
#pragma unroll
        for (int j = 0; j < 4; ++j)
            acc[i][j] = (f32x4_t){0.f, 0.f, 0.f, 0.f};

    // register staging for the in-flight K-tile
    float av[16];
    s16x8_t sbh0, sbh1, sbl0, sbl1;

#define G_LOAD(k0_)                                              \
    do {                                                         \
        *(float4*)&av[0]  = *(const float4*)(Ap + (k0_));        \
        *(float4*)&av[4]  = *(const float4*)(Ap + (k0_) + 4);    \
        *(float4*)&av[8]  = *(const float4*)(Ap + (k0_) + 8);    \
        *(float4*)&av[12] = *(const float4*)(Ap + (k0_) + 12);   \
        sbh0 = *(const s16x8_t*)(Bhp + (k0_));                   \
        sbh1 = *(const s16x8_t*)(Bhp + (k0_) + 8);               \
        sbl0 = *(const s16x8_t*)(Blp + (k0_));                   \
        sbl1 = *(const s16x8_t*)(Blp + (k0_) + 8);               \
    } while (0)

#define LDS_STORE(buf_)                                          \
    do {                                                         \
        s16x8_t h0, h1, l0, l1;                                  \
        _Pragma("unroll")                                        \
        for (int i = 0; i < 8; ++i) {                            \
            unsigned short hi = bf16rn(av[i]);                   \
            h0[i] = (short)hi;                                   \
            l0[i] = (short)bf16rn(av[i] - bf16tof(hi));          \
        }                                                        \
        _Pragma("unroll")                                        \
        for (int i = 0; i < 8; ++i) {                            \
            unsigned short hi = bf16rn(av[8 + i]);               \
            h1[i] = (short)hi;                                   \
            l1[i] = (short)bf16rn(av[8 + i] - bf16tof(hi));      \
        }                                                        \
        *(s16x8_t*)&As_hi[buf_][srow][skh]     = h0;             \
        *(s16x8_t*)&As_hi[buf_][srow][skh + 8] = h1;             \
        *(s16x8_t*)&As_lo[buf_][srow][skh]     = l0;             \
        *(s16x8_t*)&As_lo[buf_][srow][skh + 8] = l1;             \
        *(s16x8_t*)&Bs_hi[buf_][srow][skh]     = sbh0;           \
        *(s16x8_t*)&Bs_hi[buf_][srow][skh + 8] = sbh1;           \
        *(s16x8_t*)&Bs_lo[buf_][srow][skh]     = sbl0;           \
        *(s16x8_t*)&Bs_lo[buf_][srow][skh + 8] = sbl1;           \
    } while (0)

    // prologue: tile 0 into LDS[0], tile 1 in flight in registers
    G_LOAD(0);
    LDS_STORE(0);
    if (nk > 1) G_LOAD(32);
    __syncthreads();

    for (int k = 0; k < nk; ++k) {
        const int cur = k & 1;
        // issue this tile's fragment reads first (lgkm in flight)
        s16x8_t ah[4], al[4], bh[4], bl[4];
#pragma unroll
        for (int mt = 0; mt < 4; ++mt) {
            ah[mt] = *(const s16x8_t*)&As_hi[cur][wr * 64 + mt * 16 + lm][qd * 8];
            al[mt] = *(const s16x8_t*)&As_lo[cur][wr * 64 + mt * 16 + lm][qd * 8];
        }
#pragma unroll
        for (int nt = 0; nt < 4; ++nt) {
            bh[nt] = *(const s16x8_t*)&Bs_hi[cur][wc * 64 + nt * 16 + lm][qd * 8];
            bl[nt] = *(const s16x8_t*)&Bs_lo[cur][wc * 64 + nt * 16 + lm][qd * 8];
        }
        // drain in-flight registers into the other LDS buffer, then issue
        // the next prefetch (2 tiles ahead) before the MFMA cluster
        if (k + 1 < nk) {
            LDS_STORE(cur ^ 1);
            if (k + 2 < nk) G_LOAD((k + 2) << 5);
        }
#pragma unroll
        for (int mt = 0; mt < 4; ++mt)
#pragma unroll
            for (int nt = 0; nt < 4; ++nt) {
                acc[mt][nt] = __builtin_amdgcn_mfma_f32_16x16x32_bf16(ah[mt], bh[nt], acc[mt][nt], 0, 0, 0);
                acc[mt][nt] = __builtin_amdgcn_mfma_f32_16x16x32_bf16(ah[mt], bl[nt], acc[mt][nt], 0, 0, 0);
                acc[mt][nt] = __builtin_amdgcn_mfma_f32_16x16x32_bf16(al[mt], bh[nt], acc[mt][nt], 0, 0, 0);
            }
        __syncthreads();
    }
#undef G_LOAD
#undef LDS_STORE

    // epilogue: C/D layout col=lane&15, row=qd*4+reg
#pragma unroll
    for (int nt = 0; nt < 4; ++nt) {
        size_t n = n0 + wc * 64 + nt * 16 + lm;
        float bs = bias ? bias[n] : 0.f;
#pragma unroll
        for (int mt = 0; mt < 4; ++mt) {
#pragma unroll
            for (int r = 0; r < 4; ++r) {
                size_t m = m0 + wr * 64 + mt * 16 + qd * 4 + r;
                Cp[(size_t)m * ldc + n] = acc[mt][nt][r] + bs;
            }
        }
    }
}

// concat two f32 vectors
__global__ __launch_bounds__(256)
void concat2(const float* __restrict__ a, int na, const float* __restrict__ b, int nb,
             float* __restrict__ out)
{
    int i = blockIdx.x * 256 + threadIdx.x;
    if (i < na) out[i] = a[i];
    else if (i < na + nb) out[i] = b[i - na];
}

// mean over L: mean_a[b,e] = (1/L) * sum_l feats[b,l,e]   grid=(B, E/256)
__global__ __launch_bounds__(256)
void mean_kernel(const float* __restrict__ feats, float* __restrict__ mean_a)
{
    int b = blockIdx.x;
    int e = blockIdx.y * 256 + threadIdx.x;
    const float* f = feats + ((size_t)b * Lc) * Ec + e;
    float s = 0.f;
    for (int l = 0; l < Lc; ++l) s += f[(size_t)l * Ec];
    mean_a[b * Ec + e] = s * (1.0f / Lc);
}

// e[b,l] = sum_h relu(q[b,h] + keys[b,l,h]) * V_a[h] + b_va
// q comes as 4 split-K partials: q[b,h] = b_a[h] + sum_s qp[s*qstride + b*1536 + h]
__global__ __launch_bounds__(256)
void att_scores_sk(const float* __restrict__ qp, long qstride,
                   const float* __restrict__ b_a,
                   const float* __restrict__ keys,
                   const float* __restrict__ V_a, const float* __restrict__ b_va,
                   float* __restrict__ e)
{
    int pair = blockIdx.x * 4 + (threadIdx.x >> 6);
    int lane = threadIdx.x & 63;
    int b = pair / Lc;
    const float* kp = keys + (size_t)pair * Hc;
    const float* q0 = qp + (size_t)b * 1536;
    float s = 0.f;
    for (int h = lane; h < Hc; h += 64) {
        float q = b_a[h] + q0[h] + q0[qstride + h] + q0[2 * qstride + h] + q0[3 * qstride + h];
        s = fmaf(fmaxf(q + kp[h], 0.f), V_a[h], s);
    }
#pragma unroll
    for (int off = 32; off > 0; off >>= 1) s += __shfl_down(s, off);
    if (lane == 0) e[pair] = s + b_va[0];
}

// Fused: softmax over e[b,:] (in LDS) + z = sum_l alpha*feats + gate by
// sigmoid(sb) + build xcat = [z*sig(sb) | emb[tok] | h].  grid=(B,8), 256 thr.
// sb[b,j] = b_beta[j] + sum_s qp[s*qstride + b*1536 + 1024 + j]
__global__ __launch_bounds__(256)
void zxcat_fused(const float* __restrict__ e,
                 const float* __restrict__ qp, long qstride,
                 const float* __restrict__ b_beta,
                 const int* __restrict__ caption, const float* __restrict__ emb,
                 const float* __restrict__ feats, const float* __restrict__ hc,
                 float* __restrict__ xcat, int t)
{
    int b = blockIdx.x;
    int j = blockIdx.y * 256 + threadIdx.x;
    if (blockIdx.y < 2) {
        // --- per-block softmax over L (cheap, redundant across the 2 z-blocks)
        __shared__ float red[256];
        __shared__ float alpha[Lc];
        int tid = threadIdx.x;
        float ev = (tid < Lc) ? e[b * Lc + tid] : -1e30f;
        red[tid] = ev; __syncthreads();
        for (int s = 128; s > 0; s >>= 1) { if (tid < s) red[tid] = fmaxf(red[tid], red[tid + s]); __syncthreads(); }
        float m = red[0]; __syncthreads();
        float ex = (tid < Lc) ? expf(ev - m) : 0.f;
        red[tid] = ex; __syncthreads();
        for (int s = 128; s > 0; s >>= 1) { if (tid < s) red[tid] += red[tid + s]; __syncthreads(); }
        float ssum = red[0];
        if (tid < Lc) alpha[tid] = ex / ssum;
        __syncthreads();
        // --- z = sum_l alpha[l] * feats[b,l,j]   (j < 512 here)
        const float* f = feats + ((size_t)b * Lc) * Ec + j;
        float s = 0.f;
        for (int l = 0; l < Lc; ++l) s = fmaf(alpha[l], f[(size_t)l * Ec], s);
        const float* q0 = qp + (size_t)b * 1536 + 1024 + j;
        float sb = b_beta[j] + q0[0] + q0[qstride] + q0[2 * qstride] + q0[3 * qstride];
        xcat[(size_t)b * 2048 + j] = s * sigmoidf_(sb);
    } else if (j < 2 * Ec) {
        int tok = caption[b * Tc + t];
        xcat[(size_t)b * 2048 + j] = emb[(size_t)tok * Ec + (j - Ec)];
    } else {
        xcat[(size_t)b * 2048 + j] = hc[(size_t)b * 2048 + (j - 2 * Ec)];
    }
}

// LSTM elementwise over 4 split-K gate partials + bias. grid=B*H/256
__global__ __launch_bounds__(256)
void lstm_elem_sk(const float* __restrict__ gp, long gstride,
                  const float* __restrict__ b_lstm,
                  float* __restrict__ hbase, float* __restrict__ cbase, int ld)
{
    int idx = blockIdx.x * 256 + threadIdx.x;
    int b = idx >> 10;
    int j = idx & (Hc - 1);
    float gi = b_lstm[j], gf = b_lstm[Hc + j], gg = b_lstm[2 * Hc + j], go = b_lstm[3 * Hc + j];
#pragma unroll
    for (int s = 0; s < 4; ++s) {
        const float* g = gp + (size_t)s * gstride + (size_t)b * 4 * Hc;
        gi += g[j]; gf += g[Hc + j]; gg += g[2 * Hc + j]; go += g[3 * Hc + j];
    }
    float* cp = cbase + (size_t)b * ld + j;
    float* hp = hbase + (size_t)b * ld + j;
    float cn = sigmoidf_(gf) * (*cp) + sigmoidf_(gi) * tanhf(gg);
    *cp = cn;
    *hp = sigmoidf_(go) * tanhf(cn);
}

// softmax over V in place on out[b,t,:]. grid = B, 1024 threads.
// 3 read passes + 1 write (exp recomputed in the write pass — identical
// float math to the reference's stored-exp version).
__global__ __launch_bounds__(1024)
void softmax_V(float* __restrict__ out, int t)
{
    int b = blockIdx.x;
    float* p = out + ((size_t)b * Tc + t) * (size_t)Vc;
    __shared__ float red[1024];
    int tid = threadIdx.x;
    float m = -1e30f;
    for (int v = tid; v < Vc; v += 1024) m = fmaxf(m, p[v]);
    red[tid] = m; __syncthreads();
    for (int s = 512; s > 0; s >>= 1) { if (tid < s) red[tid] = fmaxf(red[tid], red[tid + s]); __syncthreads(); }
    m = red[0]; __syncthreads();
    float sum = 0.f;
    for (int v = tid; v < Vc; v += 1024) sum += expf(p[v] - m);
    red[tid] = sum; __syncthreads();
    for (int s = 512; s > 0; s >>= 1) { if (tid < s) red[tid] += red[tid + s]; __syncthreads(); }
    float inv = 1.0f / red[0];
    for (int v = tid; v < Vc; v += 1024) p[v] = expf(p[v] - m) * inv;
}

// ---------------------------------------------------------------------------
// Legacy helpers (fallback path only)
// ---------------------------------------------------------------------------
__global__ __launch_bounds__(256)
void att_scores(const float* __restrict__ q, int ldq, const float* __restrict__ keys,
                const float* __restrict__ V_a, const float* __restrict__ b_va,
                float* __restrict__ e)
{
    int pair = blockIdx.x * 4 + (threadIdx.x >> 6);
    int lane = threadIdx.x & 63;
    int b = pair / Lc;
    const float* qp = q + (size_t)b * ldq;
    const float* kp = keys + (size_t)pair * Hc;
    float s = 0.f;
    for (int h = lane; h < Hc; h += 64)
        s = fmaf(fmaxf(qp[h] + kp[h], 0.f), V_a[h], s);
#pragma unroll
    for (int off = 32; off > 0; off >>= 1) s += __shfl_down(s, off);
    if (lane == 0) e[pair] = s + b_va[0];
}

__global__ __launch_bounds__(256)
void softmax_L(float* __restrict__ e)
{
    int b = blockIdx.x;
    float* p = e + b * Lc;
    __shared__ float red[256];
    int tid = threadIdx.x;
    float m = -1e30f;
    if (tid < Lc) m = p[tid];
    red[tid] = m; __syncthreads();
    for (int s = 128; s > 0; s >>= 1) { if (tid < s) red[tid] = fmaxf(red[tid], red[tid + s]); __syncthreads(); }
    m = red[0]; __syncthreads();
    float ex = 0.f;
    if (tid < Lc) ex = expf(p[tid] - m);
    red[tid] = ex; __syncthreads();
    for (int s = 128; s > 0; s >>= 1) { if (tid < s) red[tid] += red[tid + s]; __syncthreads(); }
    if (tid < Lc) p[tid] = ex / red[0];
}

__global__ __launch_bounds__(256)
void z_kernel(const float* __restrict__ alpha, const float* __restrict__ feats,
              float* __restrict__ z)
{
    int b = blockIdx.x;
    int e = blockIdx.y * 256 + threadIdx.x;
    const float* f = feats + ((size_t)b * Lc) * Ec + e;
    const float* a = alpha + b * Lc;
    float s = 0.f;
    for (int l = 0; l < Lc; ++l) s = fmaf(a[l], f[(size_t)l * Ec], s);
    z[b * Ec + e] = s;
}

__global__ __launch_bounds__(256)
void ctx_build(const float* __restrict__ z, const float* __restrict__ sb,
               const int* __restrict__ caption, const float* __restrict__ emb,
               float* __restrict__ ctx, int t)
{
    int b = blockIdx.x;
    int j = blockIdx.y * 256 + threadIdx.x;
    float v;
    if (j < Ec) {
        v = z[b * Ec + j] * sigmoidf_(sb[b * Ec + j]);
    } else {
        int tok = caption[b * Tc + t];
        v = emb[(size_t)tok * Ec + (j - Ec)];
    }
    ctx[b * (2 * Ec) + j] = v;
}

__global__ __launch_bounds__(256)
void lstm_elem(const float* __restrict__ gates, float* __restrict__ hbase,
               float* __restrict__ cbase, int ld)
{
    int idx = blockIdx.x * 256 + threadIdx.x;
    int b = idx >> 10;
    int j = idx & (Hc - 1);
    const float* g = gates + (size_t)b * 4 * Hc;
    float gi = g[j], gf = g[Hc + j], gg = g[2 * Hc + j], go = g[3 * Hc + j];
    float* cp = cbase + (size_t)b * ld + j;
    float* hp = hbase + (size_t)b * ld + j;
    float cn = sigmoidf_(gf) * (*cp) + sigmoidf_(gi) * tanhf(gg);
    *cp = cn;
    *hp = sigmoidf_(go) * tanhf(cn);
}

__global__ __launch_bounds__(256)
void gemm_f32(const float* __restrict__ A, int lda,
              const float* __restrict__ Bm, int ldb,
              float* __restrict__ C, int ldc,
              const float* __restrict__ bias,
              int K, int accumulate)
{
    __shared__ __align__(16) float As[16][68];
    __shared__ __align__(16) float Bs[16][68];
    const int t  = threadIdx.x;
    const int tx = t & 15;
    const int ty = t >> 4;
    const size_t m0 = (size_t)blockIdx.x * 64;
    const size_t n0 = (size_t)blockIdx.y * 64;
    const int arow = t >> 2;
    const int acol = (t & 3) << 2;
    const int brow = t >> 4;
    const int bcol = (t & 15) << 2;
    const float* Aptr = A + (m0 + arow) * (size_t)lda + acol;
    const float* Bptr = Bm + (size_t)brow * ldb + n0 + bcol;
    float acc[4][4] = {};
    for (int k0 = 0; k0 < K; k0 += 16) {
        float4 av = *reinterpret_cast<const float4*>(Aptr + k0);
        float4 bv = *reinterpret_cast<const float4*>(Bptr + (size_t)k0 * ldb);
        As[acol + 0][arow] = av.x;
        As[acol + 1][arow] = av.y;
        As[acol + 2][arow] = av.z;
        As[acol + 3][arow] = av.w;
        *reinterpret_cast<float4*>(&Bs[brow][bcol]) = bv;
        __syncthreads();
#pragma unroll
        for (int k = 0; k < 16; ++k) {
            float4 a4 = *reinterpret_cast<const float4*>(&As[k][ty << 2]);
            float4 b4 = *reinterpret_cast<const float4*>(&Bs[k][tx << 2]);
            float aa[4] = {a4.x, a4.y, a4.z, a4.w};
            float bb[4] = {b4.x, b4.y, b4.z, b4.w};
#pragma unroll
            for (int i = 0; i < 4; ++i)
#pragma unroll
                for (int j = 0; j < 4; ++j)
                    acc[i][j] = fmaf(aa[i], bb[j], acc[i][j]);
        }
        __syncthreads();
    }
    float4 bv4 = {0.f, 0.f, 0.f, 0.f};
    if (bias) bv4 = *reinterpret_cast<const float4*>(&bias[n0 + (tx << 2)]);
#pragma unroll
    for (int i = 0; i < 4; ++i) {
        size_t off = (m0 + (size_t)(ty << 2) + i) * (size_t)ldc + n0 + (tx << 2);
        float4 o;
        o.x = acc[i][0] + bv4.x;
        o.y = acc[i][1] + bv4.y;
        o.z = acc[i][2] + bv4.z;
        o.w = acc[i][3] + bv4.w;
        if (accumulate) {
            float4 prev = *reinterpret_cast<const float4*>(&C[off]);
            o.x += prev.x; o.y += prev.y; o.z += prev.z; o.w += prev.w;
        }
        *reinterpret_cast<float4*>(&C[off]) = o;
    }
}

extern "C" void kernel_launch(void* const* d_in, const int* in_sizes, int n_in,
                              void* d_out, int out_size, void* d_ws, size_t ws_size,
                              hipStream_t stream)
{
    const int*   caption  = (const int*)  d_in[0];
    const float* feats    = (const float*)d_in[1];
    const float* emb      = (const float*)d_in[2];
    const float* W_init_h = (const float*)d_in[3];
    const float* b_init_h = (const float*)d_in[4];
    const float* W_init_c = (const float*)d_in[5];
    const float* b_init_c = (const float*)d_in[6];
    const float* W_a      = (const float*)d_in[7];
    const float* b_a      = (const float*)d_in[8];
    const float* U_a      = (const float*)d_in[9];
    const float* b_ua     = (const float*)d_in[10];
    const float* V_a      = (const float*)d_in[11];
    const float* b_va     = (const float*)d_in[12];
    const float* W_beta   = (const float*)d_in[13];
    const float* b_beta   = (const float*)d_in[14];
    const float* W_lstm   = (const float*)d_in[15];
    const float* U_lstm   = (const float*)d_in[16];
    const float* b_lstm   = (const float*)d_in[17];
    const float* W_out    = (const float*)d_in[18];
    const float* b_out    = (const float*)d_in[19];
    float* out = (float*)d_out;

    dim3 blk(256);

    // ---------------- fast-path workspace layout (bytes) ----------------
    char* base = (char*)d_ws;
    size_t off = 0;
    auto alloc = [&](size_t bytes) { char* p = base + off; off = (off + bytes + 15) & ~(size_t)15; return p; };

    float* keys      = (float*)alloc((size_t)Bc * Lc * Hc * 4);
    float* hc        = (float*)alloc((size_t)Bc * 2048 * 4);      // h | c per row
    float* qsb_part  = (float*)alloc((size_t)4 * Bc * 1536 * 4);  // 4 split-K partials of [q|sb]
    float* e         = (float*)alloc((size_t)Bc * Lc * 4);
    float* xcat      = (float*)alloc((size_t)Bc * 2048 * 4);      // z*sig | emb | h
    float* gate_part = (float*)alloc((size_t)4 * Bc * 4 * Hc * 4);// 4 split-K partials of gates
    float* mean_a    = (float*)alloc((size_t)Bc * Ec * 4);
    float* bcat_i    = (float*)alloc(2048 * 4);
    unsigned short* Wout_hi  = (unsigned short*)alloc((size_t)Vc * Hc * 2);
    unsigned short* Wout_lo  = (unsigned short*)alloc((size_t)Vc * Hc * 2);
    unsigned short* Wg_hi    = (unsigned short*)alloc((size_t)4096 * 2048 * 2);
    unsigned short* Wg_lo    = (unsigned short*)alloc((size_t)4096 * 2048 * 2);
    unsigned short* Wqsb_hi  = (unsigned short*)alloc((size_t)1536 * 1024 * 2);
    unsigned short* Wqsb_lo  = (unsigned short*)alloc((size_t)1536 * 1024 * 2);
    unsigned short* Ua_hi    = (unsigned short*)alloc((size_t)1024 * 512 * 2);
    unsigned short* Ua_lo    = (unsigned short*)alloc((size_t)1024 * 512 * 2);
    unsigned short* Wini_hi  = (unsigned short*)alloc((size_t)2048 * 512 * 2);
    unsigned short* Wini_lo  = (unsigned short*)alloc((size_t)2048 * 512 * 2);
    const size_t need_fast = off;

    const long QSTRIDE = (long)Bc * 1536;
    const long GSTRIDE = (long)Bc * 4 * Hc;

    if (ws_size >= need_fast) {
        // ================= fast path: split-bf16 MFMA =================
        // ---- weight prep (per call; workspace is re-poisoned each call) ----
        transpose_split<<<dim3(16, 32), blk, 0, stream>>>(U_a, 1024, Ua_hi, Ua_lo, 512);
        transpose_split<<<dim3(16, 32), blk, 0, stream>>>(W_init_h, 1024, Wini_hi, Wini_lo, 512);
        transpose_split<<<dim3(16, 32), blk, 0, stream>>>(W_init_c, 1024, Wini_hi + (size_t)1024 * 512, Wini_lo + (size_t)1024 * 512, 512);
        transpose_split<<<dim3(32, 32), blk, 0, stream>>>(W_a, 1024, Wqsb_hi, Wqsb_lo, 1024);
        transpose_split<<<dim3(32, 16), blk, 0, stream>>>(W_beta, 512, Wqsb_hi + (size_t)1024 * 1024, Wqsb_lo + (size_t)1024 * 1024, 1024);
        transpose_split<<<dim3(32, 128), blk, 0, stream>>>(W_lstm, 4096, Wg_hi, Wg_lo, 2048);
        transpose_split<<<dim3(32, 128), blk, 0, stream>>>(U_lstm, 4096, Wg_hi + 1024, Wg_lo + 1024, 2048);
        transpose_split<<<dim3(32, 1000), blk, 0, stream>>>(W_out, Vc, Wout_hi, Wout_lo, 1024);
        concat2<<<dim3(8), blk, 0, stream>>>(b_init_h, 1024, b_init_c, 1024, bcat_i);

        // ---- setup ----
        mean_kernel<<<dim3(Bc, 2), blk, 0, stream>>>(feats, mean_a);
        // hc = mean_a @ [W_init_h | W_init_c] + [b_init_h | b_init_c]
        gemm_mfma_split<<<dim3(1, 16, 1), blk, 0, stream>>>(mean_a, Ec, Wini_hi, Wini_lo, hc, 2048, bcat_i, 512, 0);
        // keys = feats @ U_a + b_ua
        gemm_mfma_split<<<dim3((Bc * Lc) / 128, 8, 1), blk, 0, stream>>>(feats, Ec, Ua_hi, Ua_lo, keys, Hc, b_ua, 512, 0);

        // ---- time steps ----
        for (int t = 0; t < Tc; ++t) {
            // qsb partials = h @ [W_a | W_beta], split-K x4 (bias folded by consumers)
            gemm_mfma_split<<<dim3(1, 12, 4), blk, 0, stream>>>(hc, 2048, Wqsb_hi, Wqsb_lo, qsb_part, 1536, nullptr, 1024, QSTRIDE);
            att_scores_sk<<<dim3((Bc * Lc) / 4), blk, 0, stream>>>(qsb_part, QSTRIDE, b_a, keys, V_a, b_va, e);
            zxcat_fused<<<dim3(Bc, 8), blk, 0, stream>>>(e, qsb_part, QSTRIDE, b_beta, caption, emb, feats, hc, xcat, t);
            // gate partials = [ctx | h] @ [W_lstm ; U_lstm], split-K x4
            gemm_mfma_split<<<dim3(1, 32, 4), blk, 0, stream>>>(xcat, 2048, Wg_hi, Wg_lo, gate_part, 4096, nullptr, 2048, GSTRIDE);
            lstm_elem_sk<<<dim3((Bc * Hc) / 256), blk, 0, stream>>>(gate_part, GSTRIDE, b_lstm, hc, hc + 1024, 2048);
            // logits into d_out slice, softmax in place
            gemm_mfma_split<<<dim3(1, 250, 1), blk, 0, stream>>>(hc, 2048, Wout_hi, Wout_lo, out + (size_t)t * Vc, (long)Tc * Vc, b_out, 1024, 0);
            softmax_V<<<dim3(Bc), dim3(1024), 0, stream>>>(out, t);
        }
        return;
    }

    // ================= legacy f32 fallback =================
    float* ws = (float*)d_ws;
    size_t foff = 0;
    float* l_keys  = ws + foff; foff += (size_t)Bc * Lc * Hc;
    float* l_h     = ws + foff; foff += (size_t)Bc * Hc;
    float* l_c     = ws + foff; foff += (size_t)Bc * Hc;
    float* l_q     = ws + foff; foff += (size_t)Bc * Hc;
    float* l_e     = ws + foff; foff += (size_t)Bc * Lc;
    float* l_sb    = ws + foff; foff += (size_t)Bc * Ec;
    float* l_z     = ws + foff; foff += (size_t)Bc * Ec;
    float* l_ctx   = ws + foff; foff += (size_t)Bc * 2 * Ec;
    float* l_gates = ws + foff; foff += (size_t)Bc * 4 * Hc;
    float* l_mean  = ws + foff; foff += (size_t)Bc * Ec;
    if (ws_size < foff * sizeof(float)) return;

    mean_kernel<<<dim3(Bc, 2), blk, 0, stream>>>(feats, l_mean);
    gemm_f32<<<dim3(Bc / 64, Hc / 64), blk, 0, stream>>>(l_mean, Ec, W_init_h, Hc, l_h, Hc, b_init_h, Ec, 0);
    gemm_f32<<<dim3(Bc / 64, Hc / 64), blk, 0, stream>>>(l_mean, Ec, W_init_c, Hc, l_c, Hc, b_init_c, Ec, 0);
    gemm_f32<<<dim3((Bc * Lc) / 64, Hc / 64), blk, 0, stream>>>(feats, Ec, U_a, Hc, l_keys, Hc, b_ua, Ec, 0);
    for (int t = 0; t < Tc; ++t) {
        gemm_f32<<<dim3(Bc / 64, Hc / 64), blk, 0, stream>>>(l_h, Hc, W_a, Hc, l_q, Hc, b_a, Hc, 0);
        att_scores<<<dim3((Bc * Lc) / 4), blk, 0, stream>>>(l_q, Hc, l_keys, V_a, b_va, l_e);
        softmax_L<<<dim3(Bc), blk, 0, stream>>>(l_e);
        z_kernel<<<dim3(Bc, 2), blk, 0, stream>>>(l_e, feats, l_z);
        gemm_f32<<<dim3(Bc / 64, Ec / 64), blk, 0, stream>>>(l_h, Hc, W_beta, Ec, l_sb, Ec, b_beta, Hc, 0);
        ctx_build<<<dim3(Bc, 4), blk, 0, stream>>>(l_z, l_sb, caption, emb, l_ctx, t);
        gemm_f32<<<dim3(Bc / 64, (4 * Hc) / 64), blk, 0, stream>>>(l_ctx, 2 * Ec, W_lstm, 4 * Hc, l_gates, 4 * Hc, b_lstm, 2 * Ec, 0);
        gemm_f32<<<dim3(Bc / 64, (4 * Hc) / 64), blk, 0, stream>>>(l_h, Hc, U_lstm, 4 * Hc, l_gates, 4 * Hc, nullptr, Hc, 1);
        lstm_elem<<<dim3((Bc * Hc) / 256), blk, 0, stream>>>(l_gates, l_h, l_c, Hc);
        gemm_f32<<<dim3(Bc / 64, Vc / 64), blk, 0, stream>>>(l_h, Hc, W_out, Vc, out + (size_t)t * Vc, Tc * Vc, b_out, Hc, 0);
        softmax_V<<<dim3(Bc), dim3(1024), 0, stream>>>(out, t);
    }
}

// Round 3
// 2972.127 us; speedup vs baseline: 2.1744x; 1.1055x over previous
//
#include <hip/hip_runtime.h>
#include <hip/hip_bf16.h>
#include <math.h>

// Problem constants (fixed by the reference)
constexpr int Bc = 128, Tc = 16, Lc = 196, Ec = 512, Hc = 1024, Vc = 32000;

typedef float f32x4_t __attribute__((ext_vector_type(4)));
typedef short s16x8_t __attribute__((ext_vector_type(8)));

__device__ __forceinline__ float sigmoidf_(float x) { return 1.0f / (1.0f + expf(-x)); }

__device__ __forceinline__ unsigned short bf16rn(float x) {
    union { float f; unsigned u; } v; v.f = x;
    unsigned r = v.u + 0x7fffu + ((v.u >> 16) & 1u);
    return (unsigned short)(r >> 16);
}
__device__ __forceinline__ float bf16tof(unsigned short h) {
    union { unsigned u; float f; } v; v.u = ((unsigned)h) << 16; return v.f;
}

// ---------------------------------------------------------------------------
// Batched weight prep: 8 transposes (src [K][N] f32 -> dhi/dlo [N][ldd]
// hi/lo bf16) + mean_a tail, all in ONE flat-grid dispatch. 256 threads.
// ---------------------------------------------------------------------------
struct TDesc {
    const float* src;
    unsigned short* dhi;
    unsigned short* dlo;
    int N, ldd, gx, base;
};
struct PrepP {
    TDesc d[8];
    int tblocks;             // total transpose blocks; mean tail follows
    const float* feats;
    float* mean_a;
};

__global__ __launch_bounds__(256)
void prep_multi(PrepP p)
{
    const int id = blockIdx.x;
    if (id >= p.tblocks) {
        // mean over L: b = idm>>1, e-chunk = idm&1
        int idm = id - p.tblocks;
        int b = idm >> 1;
        int e = (idm & 1) * 256 + threadIdx.x;
        const float* f = p.feats + ((size_t)b * Lc) * Ec + e;
        float s = 0.f;
        for (int l = 0; l < Lc; ++l) s += f[(size_t)l * Ec];
        p.mean_a[b * Ec + e] = s * (1.0f / Lc);
        return;
    }
    int di = 0;
#pragma unroll
    for (int i = 1; i < 8; ++i) if (id >= p.d[i].base) di = i;
    const TDesc d = p.d[di];
    const int lid = id - d.base;
    const int k0 = (lid % d.gx) * 32;
    const int n0 = (lid / d.gx) * 32;

    __shared__ float tile[32][33];
    const int tx = threadIdx.x & 31, ty = threadIdx.x >> 5;  // ty 0..7
#pragma unroll
    for (int i = 0; i < 4; ++i)
        tile[ty + i * 8][tx] = d.src[(size_t)(k0 + ty + i * 8) * d.N + n0 + tx];
    __syncthreads();
#pragma unroll
    for (int i = 0; i < 4; ++i) {
        int nl = ty + i * 8;
        float v = tile[tx][nl];
        unsigned short hi = bf16rn(v);
        unsigned short lo = bf16rn(v - bf16tof(hi));
        size_t off = (size_t)(n0 + nl) * d.ldd + k0 + tx;
        d.dhi[off] = hi;
        d.dlo[off] = lo;
    }
}

// ---------------------------------------------------------------------------
// Split-bf16 MFMA GEMM body: C[M,N] = A[M,K](f32) @ B[K,N] (+bias), B pre-
// transposed/split: Bhi/Blo [N][K] bf16 bits.
// acc += Ahi*Bhi + Ahi*Blo + Alo*Bhi   (lo*lo dropped, ~2^-18 relative)
// Block: 256 thr = 4 waves (2x2), tile 128x128, BK=32, 16x16x32 MFMA.
// PIPELINED (LDS dbuf + 2-deep register prefetch, 1 barrier per K-step).
// SPLIT-K via p.S: slice ksl handles K/S contiguous K; output goes to
// C + ksl*cslice (bias nullptr for split calls; consumers reduce).
// Parameterized by virtual block coords so one dispatch can co-schedule
// two independent GEMMs (gemm_dual) — poor-man's stream overlap under
// graph capture (no hipEvent* allowed).
// ---------------------------------------------------------------------------
struct GemmP {
    const float* A;
    const unsigned short* Bhi;
    const unsigned short* Blo;
    float* C;
    const float* bias;
    long ldc, cslice;
    int lda, K, gx, gy, S;
};

__device__ __forceinline__ void gemm_body(char* smem, int bx, int by, int ksl, const GemmP& p)
{
    auto As_hi = (unsigned short (*)[128][32])(smem);
    auto As_lo = (unsigned short (*)[128][32])(smem + 16384);
    auto Bs_hi = (unsigned short (*)[128][32])(smem + 32768);
    auto Bs_lo = (unsigned short (*)[128][32])(smem + 49152);

    const int t = threadIdx.x;
    const int wave = t >> 6, lane = t & 63;
    const int wr = wave >> 1, wc = wave & 1;   // wave 2x2 within 128x128 tile
    const int lm = lane & 15, qd = lane >> 4;  // fragment coords
    const size_t m0 = (size_t)bx * 128;
    const size_t n0 = (size_t)by * 128;

    const int Ksl = p.K / p.S;        // caller guarantees %32==0, >=64
    const int kbase = ksl * Ksl;

    // staging assignment: thread -> (row = t>>1, k-half = (t&1)*16)
    const int srow = t >> 1;
    const int skh  = (t & 1) * 16;

    const float* Ap = p.A + (m0 + srow) * (size_t)p.lda + skh + kbase;
    const unsigned short* Bhp = p.Bhi + (n0 + srow) * (size_t)p.K + skh + kbase;
    const unsigned short* Blp = p.Blo + (n0 + srow) * (size_t)p.K + skh + kbase;

    const int nk = Ksl >> 5;
    float* Cp = p.C + (size_t)ksl * p.cslice;

    f32x4_t acc[4][4];
#pragma unroll
    for (int i = 0; i < 4; ++i)
#pragma unroll
        for (int j = 0; j < 4; ++j)
            acc[i][j] = (f32x4_t){0.f, 0.f, 0.f, 0.f};

    // register staging for the in-flight K-tile
    float av[16];
    s16x8_t sbh0, sbh1, sbl0, sbl1;

#define G_LOAD(k0_)                                              \
    do {                                                         \
        *(float4*)&av[0]  = *(const float4*)(Ap + (k0_));        \
        *(float4*)&av[4]  = *(const float4*)(Ap + (k0_) + 4);    \
        *(float4*)&av[8]  = *(const float4*)(Ap + (k0_) + 8);    \
        *(float4*)&av[12] = *(const float4*)(Ap + (k0_) + 12);   \
        sbh0 = *(const s16x8_t*)(Bhp + (k0_));                   \
        sbh1 = *(const s16x8_t*)(Bhp + (k0_) + 8);               \
        sbl0 = *(const s16x8_t*)(Blp + (k0_));                   \
        sbl1 = *(const s16x8_t*)(Blp + (k0_) + 8);               \
    } while (0)

#define LDS_STORE(buf_)                                          \
    do {                                                         \
        s16x8_t h0, h1, l0, l1;                                  \
        _Pragma("unroll")                                        \
        for (int i = 0; i < 8; ++i) {                            \
            unsigned short hi = bf16rn(av[i]);                   \
            h0[i] = (short)hi;                                   \
            l0[i] = (short)bf16rn(av[i] - bf16tof(hi));          \
        }                                                        \
        _Pragma("unroll")                                        \
        for (int i = 0; i < 8; ++i) {                            \
            unsigned short hi = bf16rn(av[8 + i]);               \
            h1[i] = (short)hi;                                   \
            l1[i] = (short)bf16rn(av[8 + i] - bf16tof(hi));      \
        }                                                        \
        *(s16x8_t*)&As_hi[buf_][srow][skh]     = h0;             \
        *(s16x8_t*)&As_hi[buf_][srow][skh + 8] = h1;             \
        *(s16x8_t*)&As_lo[buf_][srow][skh]     = l0;             \
        *(s16x8_t*)&As_lo[buf_][srow][skh + 8] = l1;             \
        *(s16x8_t*)&Bs_hi[buf_][srow][skh]     = sbh0;           \
        *(s16x8_t*)&Bs_hi[buf_][srow][skh + 8] = sbh1;           \
        *(s16x8_t*)&Bs_lo[buf_][srow][skh]     = sbl0;           \
        *(s16x8_t*)&Bs_lo[buf_][srow][skh + 8] = sbl1;           \
    } while (0)

    // prologue: tile 0 into LDS[0], tile 1 in flight in registers
    G_LOAD(0);
    LDS_STORE(0);
    if (nk > 1) G_LOAD(32);
    __syncthreads();

    for (int k = 0; k < nk; ++k) {
        const int cur = k & 1;
        // issue this tile's fragment reads first (lgkm in flight)
        s16x8_t ah[4], al[4], bh[4], bl[4];
#pragma unroll
        for (int mt = 0; mt < 4; ++mt) {
            ah[mt] = *(const s16x8_t*)&As_hi[cur][wr * 64 + mt * 16 + lm][qd * 8];
            al[mt] = *(const s16x8_t*)&As_lo[cur][wr * 64 + mt * 16 + lm][qd * 8];
        }
#pragma unroll
        for (int nt = 0; nt < 4; ++nt) {
            bh[nt] = *(const s16x8_t*)&Bs_hi[cur][wc * 64 + nt * 16 + lm][qd * 8];
            bl[nt] = *(const s16x8_t*)&Bs_lo[cur][wc * 64 + nt * 16 + lm][qd * 8];
        }
        // drain in-flight registers into the other LDS buffer, then issue
        // the next prefetch (2 tiles ahead) before the MFMA cluster
        if (k + 1 < nk) {
            LDS_STORE(cur ^ 1);
            if (k + 2 < nk) G_LOAD((k + 2) << 5);
        }
#pragma unroll
        for (int mt = 0; mt < 4; ++mt)
#pragma unroll
            for (int nt = 0; nt < 4; ++nt) {
                acc[mt][nt] = __builtin_amdgcn_mfma_f32_16x16x32_bf16(ah[mt], bh[nt], acc[mt][nt], 0, 0, 0);
                acc[mt][nt] = __builtin_amdgcn_mfma_f32_16x16x32_bf16(ah[mt], bl[nt], acc[mt][nt], 0, 0, 0);
                acc[mt][nt] = __builtin_amdgcn_mfma_f32_16x16x32_bf16(al[mt], bh[nt], acc[mt][nt], 0, 0, 0);
            }
        __syncthreads();
    }
#undef G_LOAD
#undef LDS_STORE

    // epilogue: C/D layout col=lane&15, row=qd*4+reg
#pragma unroll
    for (int nt = 0; nt < 4; ++nt) {
        size_t n = n0 + wc * 64 + nt * 16 + lm;
        float bs = p.bias ? p.bias[n] : 0.f;
#pragma unroll
        for (int mt = 0; mt < 4; ++mt) {
#pragma unroll
            for (int r = 0; r < 4; ++r) {
                size_t m = m0 + wr * 64 + mt * 16 + qd * 4 + r;
                Cp[(size_t)m * p.ldc + n] = acc[mt][nt][r] + bs;
            }
        }
    }
}

__global__ __launch_bounds__(256)
void gemm_one(GemmP p)
{
    __shared__ __align__(16) char smem[65536];
    gemm_body(smem, blockIdx.x, blockIdx.y, blockIdx.z, p);
}

// Two independent GEMMs in one dispatch (flat grid = nA + nB blocks).
__global__ __launch_bounds__(256)
void gemm_dual(GemmP a, GemmP b)
{
    __shared__ __align__(16) char smem[65536];
    int id = blockIdx.x;
    const int na = a.gx * a.gy * a.S;
    if (id < na) {
        int by = id % a.gy; int bx = (id / a.gy) % a.gx; int kz = id / (a.gy * a.gx);
        gemm_body(smem, bx, by, kz, a);
    } else {
        id -= na;
        int by = id % b.gy; int bx = (id / b.gy) % b.gx; int kz = id / (b.gy * b.gx);
        gemm_body(smem, bx, by, kz, b);
    }
}

// concat two f32 vectors
__global__ __launch_bounds__(256)
void concat2(const float* __restrict__ a, int na, const float* __restrict__ b, int nb,
             float* __restrict__ out)
{
    int i = blockIdx.x * 256 + threadIdx.x;
    if (i < na) out[i] = a[i];
    else if (i < na + nb) out[i] = b[i - na];
}

// mean over L (fallback path): grid=(B, E/256)
__global__ __launch_bounds__(256)
void mean_kernel(const float* __restrict__ feats, float* __restrict__ mean_a)
{
    int b = blockIdx.x;
    int e = blockIdx.y * 256 + threadIdx.x;
    const float* f = feats + ((size_t)b * Lc) * Ec + e;
    float s = 0.f;
    for (int l = 0; l < Lc; ++l) s += f[(size_t)l * Ec];
    mean_a[b * Ec + e] = s * (1.0f / Lc);
}

// e[b,l] = sum_h relu(q[b,h] + keys[b,l,h]) * V_a[h] + b_va ; split-K q.
// Standalone version for step 0 (256 thr, 4 pairs/block).
__global__ __launch_bounds__(256)
void att_scores_sk(const float* __restrict__ qp, long qstride,
                   const float* __restrict__ b_a,
                   const float* __restrict__ keys,
                   const float* __restrict__ V_a, const float* __restrict__ b_va,
                   float* __restrict__ e)
{
    int pair = blockIdx.x * 4 + (threadIdx.x >> 6);
    int lane = threadIdx.x & 63;
    int b = pair / Lc;
    const float* kp = keys + (size_t)pair * Hc;
    const float* q0 = qp + (size_t)b * 1536;
    float s = 0.f;
    for (int h = lane; h < Hc; h += 64) {
        float q = b_a[h] + q0[h] + q0[qstride + h] + q0[2 * qstride + h] + q0[3 * qstride + h];
        s = fmaf(fmaxf(q + kp[h], 0.f), V_a[h], s);
    }
#pragma unroll
    for (int off = 32; off > 0; off >>= 1) s += __shfl_down(s, off);
    if (lane == 0) e[pair] = s + b_va[0];
}

// Combined dispatch: softmax over V for step t (blocks [0,128)) AND
// attention scores for step t+1 (blocks >= 128, 16 waves = 16 pairs each).
// The two are independent (both depend only on state produced earlier in
// the stream); co-scheduling overlaps the BW-bound softmax with the
// keys-streaming att phase.  grid = 128 (+ 1568 when att enabled).
__global__ __launch_bounds__(1024)
void smv_att(float* __restrict__ out, int t,
             const float* __restrict__ qp, long qstride,
             const float* __restrict__ b_a,
             const float* __restrict__ keys,
             const float* __restrict__ V_a, const float* __restrict__ b_va,
             float* __restrict__ e)
{
    __shared__ float red[1024];
    if (blockIdx.x < 128) {
        int b = blockIdx.x;
        float* p = out + ((size_t)b * Tc + t) * (size_t)Vc;
        int tid = threadIdx.x;
        float m = -1e30f;
        for (int v = tid; v < Vc; v += 1024) m = fmaxf(m, p[v]);
        red[tid] = m; __syncthreads();
        for (int s = 512; s > 0; s >>= 1) { if (tid < s) red[tid] = fmaxf(red[tid], red[tid + s]); __syncthreads(); }
        m = red[0]; __syncthreads();
        float sum = 0.f;
        for (int v = tid; v < Vc; v += 1024) sum += expf(p[v] - m);
        red[tid] = sum; __syncthreads();
        for (int s = 512; s > 0; s >>= 1) { if (tid < s) red[tid] += red[tid + s]; __syncthreads(); }
        float inv = 1.0f / red[0];
        for (int v = tid; v < Vc; v += 1024) p[v] = expf(p[v] - m) * inv;
    } else {
        int wave = threadIdx.x >> 6, lane = threadIdx.x & 63;
        int pair = (blockIdx.x - 128) * 16 + wave;
        int b = pair / Lc;
        const float* kp = keys + (size_t)pair * Hc;
        const float* q0 = qp + (size_t)b * 1536;
        float s = 0.f;
        for (int h = lane; h < Hc; h += 64) {
            float q = b_a[h] + q0[h] + q0[qstride + h] + q0[2 * qstride + h] + q0[3 * qstride + h];
            s = fmaf(fmaxf(q + kp[h], 0.f), V_a[h], s);
        }
#pragma unroll
        for (int off = 32; off > 0; off >>= 1) s += __shfl_down(s, off);
        if (lane == 0) e[pair] = s + b_va[0];
    }
}

// Fused: softmax over e[b,:] (in LDS) + z = sum_l alpha*feats + gate by
// sigmoid(sb) + build xcat = [z*sig(sb) | emb[tok] | h].  grid=(B,8), 256 thr.
__global__ __launch_bounds__(256)
void zxcat_fused(const float* __restrict__ e,
                 const float* __restrict__ qp, long qstride,
                 const float* __restrict__ b_beta,
                 const int* __restrict__ caption, const float* __restrict__ emb,
                 const float* __restrict__ feats, const float* __restrict__ hc,
                 float* __restrict__ xcat, int t)
{
    int b = blockIdx.x;
    int j = blockIdx.y * 256 + threadIdx.x;
    if (blockIdx.y < 2) {
        // --- per-block softmax over L (cheap, redundant across the 2 z-blocks)
        __shared__ float red[256];
        __shared__ float alpha[Lc];
        int tid = threadIdx.x;
        float ev = (tid < Lc) ? e[b * Lc + tid] : -1e30f;
        red[tid] = ev; __syncthreads();
        for (int s = 128; s > 0; s >>= 1) { if (tid < s) red[tid] = fmaxf(red[tid], red[tid + s]); __syncthreads(); }
        float m = red[0]; __syncthreads();
        float ex = (tid < Lc) ? expf(ev - m) : 0.f;
        red[tid] = ex; __syncthreads();
        for (int s = 128; s > 0; s >>= 1) { if (tid < s) red[tid] += red[tid + s]; __syncthreads(); }
        float ssum = red[0];
        if (tid < Lc) alpha[tid] = ex / ssum;
        __syncthreads();
        // --- z = sum_l alpha[l] * feats[b,l,j]   (j < 512 here)
        const float* f = feats + ((size_t)b * Lc) * Ec + j;
        float s = 0.f;
        for (int l = 0; l < Lc; ++l) s = fmaf(alpha[l], f[(size_t)l * Ec], s);
        const float* q0 = qp + (size_t)b * 1536 + 1024 + j;
        float sb = b_beta[j] + q0[0] + q0[qstride] + q0[2 * qstride] + q0[3 * qstride];
        xcat[(size_t)b * 2048 + j] = s * sigmoidf_(sb);
    } else if (j < 2 * Ec) {
        int tok = caption[b * Tc + t];
        xcat[(size_t)b * 2048 + j] = emb[(size_t)tok * Ec + (j - Ec)];
    } else {
        xcat[(size_t)b * 2048 + j] = hc[(size_t)b * 2048 + (j - 2 * Ec)];
    }
}

// LSTM elementwise over 4 split-K gate partials + bias. grid=B*H/256
__global__ __launch_bounds__(256)
void lstm_elem_sk(const float* __restrict__ gp, long gstride,
                  const float* __restrict__ b_lstm,
                  float* __restrict__ hbase, float* __restrict__ cbase, int ld)
{
    int idx = blockIdx.x * 256 + threadIdx.x;
    int b = idx >> 10;
    int j = idx & (Hc - 1);
    float gi = b_lstm[j], gf = b_lstm[Hc + j], gg = b_lstm[2 * Hc + j], go = b_lstm[3 * Hc + j];
#pragma unroll
    for (int s = 0; s < 4; ++s) {
        const float* g = gp + (size_t)s * gstride + (size_t)b * 4 * Hc;
        gi += g[j]; gf += g[Hc + j]; gg += g[2 * Hc + j]; go += g[3 * Hc + j];
    }
    float* cp = cbase + (size_t)b * ld + j;
    float* hp = hbase + (size_t)b * ld + j;
    float cn = sigmoidf_(gf) * (*cp) + sigmoidf_(gi) * tanhf(gg);
    *cp = cn;
    *hp = sigmoidf_(go) * tanhf(cn);
}

// softmax over V in place (fallback path). grid = B, 1024 threads.
__global__ __launch_bounds__(1024)
void softmax_V(float* __restrict__ out, int t)
{
    int b = blockIdx.x;
    float* p = out + ((size_t)b * Tc + t) * (size_t)Vc;
    __shared__ float red[1024];
    int tid = threadIdx.x;
    float m = -1e30f;
    for (int v = tid; v < Vc; v += 1024) m = fmaxf(m, p[v]);
    red[tid] = m; __syncthreads();
    for (int s = 512; s > 0; s >>= 1) { if (tid < s) red[tid] = fmaxf(red[tid], red[tid + s]); __syncthreads(); }
    m = red[0]; __syncthreads();
    float sum = 0.f;
    for (int v = tid; v < Vc; v += 1024) sum += expf(p[v] - m);
    red[tid] = sum; __syncthreads();
    for (int s = 512; s > 0; s >>= 1) { if (tid < s) red[tid] += red[tid + s]; __syncthreads(); }
    float inv = 1.0f / red[0];
    for (int v = tid; v < Vc; v += 1024) p[v] = expf(p[v] - m) * inv;
}

// ---------------------------------------------------------------------------
// Legacy helpers (fallback path only)
// ---------------------------------------------------------------------------
__global__ __launch_bounds__(256)
void att_scores(const float* __restrict__ q, int ldq, const float* __restrict__ keys,
                const float* __restrict__ V_a, const float* __restrict__ b_va,
                float* __restrict__ e)
{
    int pair = blockIdx.x * 4 + (threadIdx.x >> 6);
    int lane = threadIdx.x & 63;
    int b = pair / Lc;
    const float* qp = q + (size_t)b * ldq;
    const float* kp = keys + (size_t)pair * Hc;
    float s = 0.f;
    for (int h = lane; h < Hc; h += 64)
        s = fmaf(fmaxf(qp[h] + kp[h], 0.f), V_a[h], s);
#pragma unroll
    for (int off = 32; off > 0; off >>= 1) s += __shfl_down(s, off);
    if (lane == 0) e[pair] = s + b_va[0];
}

__global__ __launch_bounds__(256)
void softmax_L(float* __restrict__ e)
{
    int b = blockIdx.x;
    float* p = e + b * Lc;
    __shared__ float red[256];
    int tid = threadIdx.x;
    float m = -1e30f;
    if (tid < Lc) m = p[tid];
    red[tid] = m; __syncthreads();
    for (int s = 128; s > 0; s >>= 1) { if (tid < s) red[tid] = fmaxf(red[tid], red[tid + s]); __syncthreads(); }
    m = red[0]; __syncthreads();
    float ex = 0.f;
    if (tid < Lc) ex = expf(p[tid] - m);
    red[tid] = ex; __syncthreads();
    for (int s = 128; s > 0; s >>= 1) { if (tid < s) red[tid] += red[tid + s]; __syncthreads(); }
    if (tid < Lc) p[tid] = ex / red[0];
}

__global__ __launch_bounds__(256)
void z_kernel(const float* __restrict__ alpha, const float* __restrict__ feats,
              float* __restrict__ z)
{
    int b = blockIdx.x;
    int e = blockIdx.y * 256 + threadIdx.x;
    const float* f = feats + ((size_t)b * Lc) * Ec + e;
    const float* a = alpha + b * Lc;
    float s = 0.f;
    for (int l = 0; l < Lc; ++l) s = fmaf(a[l], f[(size_t)l * Ec], s);
    z[b * Ec + e] = s;
}

__global__ __launch_bounds__(256)
void ctx_build(const float* __restrict__ z, const float* __restrict__ sb,
               const int* __restrict__ caption, const float* __restrict__ emb,
               float* __restrict__ ctx, int t)
{
    int b = blockIdx.x;
    int j = blockIdx.y * 256 + threadIdx.x;
    float v;
    if (j < Ec) {
        v = z[b * Ec + j] * sigmoidf_(sb[b * Ec + j]);
    } else {
        int tok = caption[b * Tc + t];
        v = emb[(size_t)tok * Ec + (j - Ec)];
    }
    ctx[b * (2 * Ec) + j] = v;
}

__global__ __launch_bounds__(256)
void lstm_elem(const float* __restrict__ gates, float* __restrict__ hbase,
               float* __restrict__ cbase, int ld)
{
    int idx = blockIdx.x * 256 + threadIdx.x;
    int b = idx >> 10;
    int j = idx & (Hc - 1);
    const float* g = gates + (size_t)b * 4 * Hc;
    float gi = g[j], gf = g[Hc + j], gg = g[2 * Hc + j], go = g[3 * Hc + j];
    float* cp = cbase + (size_t)b * ld + j;
    float* hp = hbase + (size_t)b * ld + j;
    float cn = sigmoidf_(gf) * (*cp) + sigmoidf_(gi) * tanhf(gg);
    *cp = cn;
    *hp = sigmoidf_(go) * tanhf(cn);
}

__global__ __launch_bounds__(256)
void gemm_f32(const float* __restrict__ A, int lda,
              const float* __restrict__ Bm, int ldb,
              float* __restrict__ C, int ldc,
              const float* __restrict__ bias,
              int K, int accumulate)
{
    __shared__ __align__(16) float As[16][68];
    __shared__ __align__(16) float Bs[16][68];
    const int t  = threadIdx.x;
    const int tx = t & 15;
    const int ty = t >> 4;
    const size_t m0 = (size_t)blockIdx.x * 64;
    const size_t n0 = (size_t)blockIdx.y * 64;
    const int arow = t >> 2;
    const int acol = (t & 3) << 2;
    const int brow = t >> 4;
    const int bcol = (t & 15) << 2;
    const float* Aptr = A + (m0 + arow) * (size_t)lda + acol;
    const float* Bptr = Bm + (size_t)brow * ldb + n0 + bcol;
    float acc[4][4] = {};
    for (int k0 = 0; k0 < K; k0 += 16) {
        float4 av = *reinterpret_cast<const float4*>(Aptr + k0);
        float4 bv = *reinterpret_cast<const float4*>(Bptr + (size_t)k0 * ldb);
        As[acol + 0][arow] = av.x;
        As[acol + 1][arow] = av.y;
        As[acol + 2][arow] = av.z;
        As[acol + 3][arow] = av.w;
        *reinterpret_cast<float4*>(&Bs[brow][bcol]) = bv;
        __syncthreads();
#pragma unroll
        for (int k = 0; k < 16; ++k) {
            float4 a4 = *reinterpret_cast<const float4*>(&As[k][ty << 2]);
            float4 b4 = *reinterpret_cast<const float4*>(&Bs[k][tx << 2]);
            float aa[4] = {a4.x, a4.y, a4.z, a4.w};
            float bb[4] = {b4.x, b4.y, b4.z, b4.w};
#pragma unroll
            for (int i = 0; i < 4; ++i)
#pragma unroll
                for (int j = 0; j < 4; ++j)
                    acc[i][j] = fmaf(aa[i], bb[j], acc[i][j]);
        }
        __syncthreads();
    }
    float4 bv4 = {0.f, 0.f, 0.f, 0.f};
    if (bias) bv4 = *reinterpret_cast<const float4*>(&bias[n0 + (tx << 2)]);
#pragma unroll
    for (int i = 0; i < 4; ++i) {
        size_t off = (m0 + (size_t)(ty << 2) + i) * (size_t)ldc + n0 + (tx << 2);
        float4 o;
        o.x = acc[i][0] + bv4.x;
        o.y = acc[i][1] + bv4.y;
        o.z = acc[i][2] + bv4.z;
        o.w = acc[i][3] + bv4.w;
        if (accumulate) {
            float4 prev = *reinterpret_cast<const float4*>(&C[off]);
            o.x += prev.x; o.y += prev.y; o.z += prev.z; o.w += prev.w;
        }
        *reinterpret_cast<float4*>(&C[off]) = o;
    }
}

extern "C" void kernel_launch(void* const* d_in, const int* in_sizes, int n_in,
                              void* d_out, int out_size, void* d_ws, size_t ws_size,
                              hipStream_t stream)
{
    const int*   caption  = (const int*)  d_in[0];
    const float* feats    = (const float*)d_in[1];
    const float* emb      = (const float*)d_in[2];
    const float* W_init_h = (const float*)d_in[3];
    const float* b_init_h = (const float*)d_in[4];
    const float* W_init_c = (const float*)d_in[5];
    const float* b_init_c = (const float*)d_in[6];
    const float* W_a      = (const float*)d_in[7];
    const float* b_a      = (const float*)d_in[8];
    const float* U_a      = (const float*)d_in[9];
    const float* b_ua     = (const float*)d_in[10];
    const float* V_a      = (const float*)d_in[11];
    const float* b_va     = (const float*)d_in[12];
    const float* W_beta   = (const float*)d_in[13];
    const float* b_beta   = (const float*)d_in[14];
    const float* W_lstm   = (const float*)d_in[15];
    const float* U_lstm   = (const float*)d_in[16];
    const float* b_lstm   = (const float*)d_in[17];
    const float* W_out    = (const float*)d_in[18];
    const float* b_out    = (const float*)d_in[19];
    float* out = (float*)d_out;

    dim3 blk(256);

    // ---------------- fast-path workspace layout (bytes) ----------------
    char* base = (char*)d_ws;
    size_t off = 0;
    auto alloc = [&](size_t bytes) { char* p = base + off; off = (off + bytes + 15) & ~(size_t)15; return p; };

    float* keys      = (float*)alloc((size_t)Bc * Lc * Hc * 4);
    float* hc        = (float*)alloc((size_t)Bc * 2048 * 4);      // h | c per row
    float* qsb_part  = (float*)alloc((size_t)4 * Bc * 1536 * 4);  // 4 split-K partials of [q|sb]
    float* e         = (float*)alloc((size_t)Bc * Lc * 4);
    float* xcat      = (float*)alloc((size_t)Bc * 2048 * 4);      // z*sig | emb | h
    float* gate_part = (float*)alloc((size_t)4 * Bc * 4 * Hc * 4);// 4 split-K partials of gates
    float* mean_a    = (float*)alloc((size_t)Bc * Ec * 4);
    float* bcat_i    = (float*)alloc(2048 * 4);
    unsigned short* Wout_hi  = (unsigned short*)alloc((size_t)Vc * Hc * 2);
    unsigned short* Wout_lo  = (unsigned short*)alloc((size_t)Vc * Hc * 2);
    unsigned short* Wg_hi    = (unsigned short*)alloc((size_t)4096 * 2048 * 2);
    unsigned short* Wg_lo    = (unsigned short*)alloc((size_t)4096 * 2048 * 2);
    unsigned short* Wqsb_hi  = (unsigned short*)alloc((size_t)1536 * 1024 * 2);
    unsigned short* Wqsb_lo  = (unsigned short*)alloc((size_t)1536 * 1024 * 2);
    unsigned short* Ua_hi    = (unsigned short*)alloc((size_t)1024 * 512 * 2);
    unsigned short* Ua_lo    = (unsigned short*)alloc((size_t)1024 * 512 * 2);
    unsigned short* Wini_hi  = (unsigned short*)alloc((size_t)2048 * 512 * 2);
    unsigned short* Wini_lo  = (unsigned short*)alloc((size_t)2048 * 512 * 2);
    const size_t need_fast = off;

    const long QSTRIDE = (long)Bc * 1536;
    const long GSTRIDE = (long)Bc * 4 * Hc;

    if (ws_size >= need_fast) {
        // ================= fast path: split-bf16 MFMA =================
        // ---- batched weight prep + mean (one dispatch) ----
        PrepP pp;
        int pb = 0;
        auto addT = [&](const float* src, int N, unsigned short* dhi, unsigned short* dlo,
                        int ldd, int gx, int gy, int slot) {
            pp.d[slot] = TDesc{src, dhi, dlo, N, ldd, gx, pb};
            pb += gx * gy;
        };
        addT(W_out,    Vc,   Wout_hi, Wout_lo, 1024, 32, 1000, 0);  // biggest first
        addT(W_lstm,   4096, Wg_hi,   Wg_lo,   2048, 32, 128, 1);
        addT(U_lstm,   4096, Wg_hi + 1024, Wg_lo + 1024, 2048, 32, 128, 2);
        addT(W_a,      1024, Wqsb_hi, Wqsb_lo, 1024, 32, 32, 3);
        addT(W_beta,   512,  Wqsb_hi + (size_t)1024 * 1024, Wqsb_lo + (size_t)1024 * 1024, 1024, 32, 16, 4);
        addT(U_a,      1024, Ua_hi,   Ua_lo,   512, 16, 32, 5);
        addT(W_init_h, 1024, Wini_hi, Wini_lo, 512, 16, 32, 6);
        addT(W_init_c, 1024, Wini_hi + (size_t)1024 * 512, Wini_lo + (size_t)1024 * 512, 512, 16, 32, 7);
        pp.tblocks = pb;
        pp.feats = feats;
        pp.mean_a = mean_a;
        prep_multi<<<dim3(pb + 256), blk, 0, stream>>>(pp);
        concat2<<<dim3(8), blk, 0, stream>>>(b_init_h, 1024, b_init_c, 1024, bcat_i);

        auto mkg = [](const float* A, int lda, const unsigned short* bh, const unsigned short* bl,
                      float* C, long ldc, const float* bias, int K, long cslice,
                      int gx, int gy, int S) {
            GemmP p; p.A = A; p.lda = lda; p.Bhi = bh; p.Blo = bl; p.C = C; p.ldc = ldc;
            p.bias = bias; p.K = K; p.cslice = cslice; p.gx = gx; p.gy = gy; p.S = S; return p;
        };
        GemmP g_init = mkg(mean_a, Ec, Wini_hi, Wini_lo, hc, 2048, bcat_i, 512, 0, 1, 16, 1);
        GemmP g_keys = mkg(feats, Ec, Ua_hi, Ua_lo, keys, Hc, b_ua, 512, 0, 196, 8, 1);
        GemmP g_qsb  = mkg(hc, 2048, Wqsb_hi, Wqsb_lo, qsb_part, 1536, nullptr, 1024, QSTRIDE, 1, 12, 4);
        GemmP g_gate = mkg(xcat, 2048, Wg_hi, Wg_lo, gate_part, 4096, nullptr, 2048, GSTRIDE, 1, 32, 4);

        // ---- setup: hc = init GEMM; then {keys || qsb(0)} co-scheduled ----
        gemm_one<<<dim3(1, 16, 1), blk, 0, stream>>>(g_init);
        gemm_dual<<<dim3(196 * 8 + 48), blk, 0, stream>>>(g_keys, g_qsb);
        att_scores_sk<<<dim3((Bc * Lc) / 4), blk, 0, stream>>>(qsb_part, QSTRIDE, b_a, keys, V_a, b_va, e);

        // ---- time steps ----
        for (int t = 0; t < Tc; ++t) {
            zxcat_fused<<<dim3(Bc, 8), blk, 0, stream>>>(e, qsb_part, QSTRIDE, b_beta, caption, emb, feats, hc, xcat, t);
            gemm_one<<<dim3(1, 32, 4), blk, 0, stream>>>(g_gate);
            lstm_elem_sk<<<dim3((Bc * Hc) / 256), blk, 0, stream>>>(gate_part, GSTRIDE, b_lstm, hc, hc + 1024, 2048);
            // W_out(t) co-scheduled with qsb(t+1): both depend only on new h
            GemmP g_wout = mkg(hc, 2048, Wout_hi, Wout_lo, out + (size_t)t * Vc, (long)Tc * Vc, b_out, 1024, 0, 1, 250, 1);
            if (t < Tc - 1)
                gemm_dual<<<dim3(250 + 48), blk, 0, stream>>>(g_wout, g_qsb);
            else
                gemm_one<<<dim3(1, 250, 1), blk, 0, stream>>>(g_wout);
            // softmax_V(t) co-scheduled with att(t+1)
            int natt = (t < Tc - 1) ? (Bc * Lc) / 16 : 0;
            smv_att<<<dim3(128 + natt), dim3(1024), 0, stream>>>(out, t, qsb_part, QSTRIDE, b_a, keys, V_a, b_va, e);
        }
        return;
    }

    // ================= legacy f32 fallback =================
    float* ws = (float*)d_ws;
    size_t foff = 0;
    float* l_keys  = ws + foff; foff += (size_t)Bc * Lc * Hc;
    float* l_h     = ws + foff; foff += (size_t)Bc * Hc;
    float* l_c     = ws + foff; foff += (size_t)Bc * Hc;
    float* l_q     = ws + foff; foff += (size_t)Bc * Hc;
    float* l_e     = ws + foff; foff += (size_t)Bc * Lc;
    float* l_sb    = ws + foff; foff += (size_t)Bc * Ec;
    float* l_z     = ws + foff; foff += (size_t)Bc * Ec;
    float* l_ctx   = ws + foff; foff += (size_t)Bc * 2 * Ec;
    float* l_gates = ws + foff; foff += (size_t)Bc * 4 * Hc;
    float* l_mean  = ws + foff; foff += (size_t)Bc * Ec;
    if (ws_size < foff * sizeof(float)) return;

    mean_kernel<<<dim3(Bc, 2), blk, 0, stream>>>(feats, l_mean);
    gemm_f32<<<dim3(Bc / 64, Hc / 64), blk, 0, stream>>>(l_mean, Ec, W_init_h, Hc, l_h, Hc, b_init_h, Ec, 0);
    gemm_f32<<<dim3(Bc / 64, Hc / 64), blk, 0, stream>>>(l_mean, Ec, W_init_c, Hc, l_c, Hc, b_init_c, Ec, 0);
    gemm_f32<<<dim3((Bc * Lc) / 64, Hc / 64), blk, 0, stream>>>(feats, Ec, U_a, Hc, l_keys, Hc, b_ua, Ec, 0);
    for (int t = 0; t < Tc; ++t) {
        gemm_f32<<<dim3(Bc / 64, Hc / 64), blk, 0, stream>>>(l_h, Hc, W_a, Hc, l_q, Hc, b_a, Hc, 0);
        att_scores<<<dim3((Bc * Lc) / 4), blk, 0, stream>>>(l_q, Hc, l_keys, V_a, b_va, l_e);
        softmax_L<<<dim3(Bc), blk, 0, stream>>>(l_e);
        z_kernel<<<dim3(Bc, 2), blk, 0, stream>>>(l_e, feats, l_z);
        gemm_f32<<<dim3(Bc / 64, Ec / 64), blk, 0, stream>>>(l_h, Hc, W_beta, Ec, l_sb, Ec, b_beta, Hc, 0);
        ctx_build<<<dim3(Bc, 4), blk, 0, stream>>>(l_z, l_sb, caption, emb, l_ctx, t);
        gemm_f32<<<dim3(Bc / 64, (4 * Hc) / 64), blk, 0, stream>>>(l_ctx, 2 * Ec, W_lstm, 4 * Hc, l_gates, 4 * Hc, b_lstm, 2 * Ec, 0);
        gemm_f32<<<dim3(Bc / 64, (4 * Hc) / 64), blk, 0, stream>>>(l_h, Hc, U_lstm, 4 * Hc, l_gates, 4 * Hc, nullptr, Hc, 1);
        lstm_elem<<<dim3((Bc * Hc) / 256), blk, 0, stream>>>(l_gates, l_h, l_c, Hc);
        gemm_f32<<<dim3(Bc / 64, Vc / 64), blk, 0, stream>>>(l_h, Hc, W_out, Vc, out + (size_t)t * Vc, Tc * Vc, b_out, Hc, 0);
        softmax_V<<<dim3(Bc), dim3(1024), 0, stream>>>(out, t);
    }
}